// Round 1
// baseline (582.229 us; speedup 1.0000x reference)
//
#include <hip/hip_runtime.h>
#include <math.h>

#define BB 8
#define TT 288
#define NN 2000
#define FLEN 145
#define EE 128
#define IDD 16
#define HH 128
#define DKK 144
#define KTOP 20

typedef _Float16 half8 __attribute__((ext_vector_type(8)));
typedef float f32x4 __attribute__((ext_vector_type(4)));
typedef unsigned short ushort_t;

// ---- workspace layout (float offsets) ----
#define OFF_TW  ((size_t)0)
#define SZ_TW   ((size_t)TT*FLEN*2)
#define OFF_XF  (OFF_TW + SZ_TW)
#define SZ_XF   ((size_t)BB*FLEN*NN)
#define OFF_ICN (OFF_XF + SZ_XF)
#define OFF_IRN (OFF_ICN + (size_t)BB*FLEN)
#define OFF_XE  (OFF_IRN + (size_t)BB*NN)   // after k_x1 consumes xe, region is reused as x1 hi/lo fp16 (interleaved per-slot)
#define SZ_BNH  ((size_t)BB*NN*HH)
#define OFF_X1  (OFF_XE + SZ_BNH)
#define OFF_ADP (OFF_X1 + SZ_BNH)           // holds adp hi/lo fp16 (interleaved per-slot), never fp32
#define OFF_CSW (OFF_ADP + SZ_BNH)
#define OFF_LNS (OFF_CSW + HH)
#define OFF_LNF (OFF_LNS + 16)

// fused adj+softmax LDS: 16-row cache (stride 2064 floats -> 2-way-max bank
// aliasing on the 4-quad epilogue writes, free per m136) + per-wave topk scratch
#define CACHE_W 2064
#define FUSED_LDS_BYTES ((16 * CACHE_W + 2 * 8 * 64) * 4)

__device__ __forceinline__ float wredSum(float v) {
#pragma unroll
  for (int o = 32; o > 0; o >>= 1) v += __shfl_down(v, o, 64);
  return v;
}
__device__ __forceinline__ float wredMax(float v) {
#pragma unroll
  for (int o = 32; o > 0; o >>= 1) v = fmaxf(v, __shfl_down(v, o, 64));
  return v;
}
// butterfly variants: result valid in ALL lanes (no broadcast needed)
__device__ __forceinline__ float wredSumAll(float v) {
#pragma unroll
  for (int o = 32; o > 0; o >>= 1) v += __shfl_xor(v, o, 64);
  return v;
}
__device__ __forceinline__ float wredMaxAll(float v) {
#pragma unroll
  for (int o = 32; o > 0; o >>= 1) v = fmaxf(v, __shfl_xor(v, o, 64));
  return v;
}

// fp16 hi/lo split: v = hi + lo + O(2^-22 * v)
__device__ __forceinline__ void split16(float v, ushort_t& hi, ushort_t& lo) {
  _Float16 h = (_Float16)v;
  _Float16 l = (_Float16)(v - (float)h);
  union { _Float16 f; ushort_t u; } a, b;
  a.f = h; b.f = l;
  hi = a.u; lo = b.u;
}

// colsum of Wxabs + zero LN accumulators
__global__ void k_init(const float* __restrict__ Wx, float* __restrict__ csw,
                       float* __restrict__ lns) {
  int k = threadIdx.x;
  float s = 0.f;
  for (int h = 0; h < HH; ++h) s += Wx[h * HH + k];
  csw[k] = s;
  if (k < 16) lns[k] = 0.f;
}

// twiddles: exact int reduction of angle
__global__ void k_tw(float* __restrict__ tw) {
  int id = blockIdx.x * 256 + threadIdx.x;
  if (id >= TT * FLEN) return;
  int t = id / FLEN, f = id % FLEN;
  int r = (t * f) % TT;
  double th = -2.0 * 3.14159265358979323846 * (double)r / (double)TT;
  tw[2 * id]     = (float)cos(th);
  tw[2 * id + 1] = (float)sin(th);
}

// xf[b][f][n] = |rfft(x[b,:,n])[f]|
__global__ void k_dft(const float* __restrict__ x, const float* __restrict__ tw,
                      float* __restrict__ xf) {
  __shared__ __align__(16) float Xs[16][128];
  __shared__ __align__(16) float TWs[16][32][2];
  const int b = blockIdx.z;
  const int f0 = blockIdx.y * 32;
  const int n0 = blockIdx.x * 128;
  const int tid = threadIdx.x;
  const int tn = tid & 31;
  const int tf = tid >> 5;
  float ar[4][4] = {}, ai[4][4] = {};
  for (int t0 = 0; t0 < TT; t0 += 16) {
    __syncthreads();
    for (int l = tid; l < 512; l += 256) {
      int row = l >> 5, q = l & 31;
      int n = n0 + q * 4;
      const float* src = x + ((size_t)b * TT + (t0 + row)) * NN + n;
      float4 v = make_float4(0, 0, 0, 0);
      if (n + 3 < NN) v = *(const float4*)src;
      else {
        if (n + 0 < NN) v.x = src[0];
        if (n + 1 < NN) v.y = src[1];
        if (n + 2 < NN) v.z = src[2];
        if (n + 3 < NN) v.w = src[3];
      }
      *(float4*)&Xs[row][q * 4] = v;
    }
    for (int l = tid; l < 512; l += 256) {
      int row = l >> 5, ff = l & 31;
      int f = f0 + ff;
      float2 cs = make_float2(0, 0);
      if (f < FLEN) cs = *(const float2*)&tw[((size_t)(t0 + row) * FLEN + f) * 2];
      *(float2*)&TWs[row][ff][0] = cs;
    }
    __syncthreads();
#pragma unroll 4
    for (int t = 0; t < 16; ++t) {
      float4 xv = *(float4*)&Xs[t][tn * 4];
      float xx[4] = {xv.x, xv.y, xv.z, xv.w};
      float4 p0 = *(float4*)&TWs[t][tf * 4][0];
      float4 p1 = *(float4*)&TWs[t][tf * 4 + 2][0];
      float c[4] = {p0.x, p0.z, p1.x, p1.z};
      float s[4] = {p0.y, p0.w, p1.y, p1.w};
#pragma unroll
      for (int i = 0; i < 4; ++i)
#pragma unroll
        for (int j = 0; j < 4; ++j) {
          ar[i][j] = fmaf(xx[j], c[i], ar[i][j]);
          ai[i][j] = fmaf(xx[j], s[i], ai[i][j]);
        }
    }
  }
#pragma unroll
  for (int i = 0; i < 4; ++i) {
    int f = f0 + tf * 4 + i;
    if (f >= FLEN) continue;
    float* dst = &xf[((size_t)b * FLEN + f) * NN];
    float o[4];
#pragma unroll
    for (int j = 0; j < 4; ++j)
      o[j] = sqrtf(ar[i][j] * ar[i][j] + ai[i][j] * ai[i][j]);
    int n = n0 + tn * 4;
    if (n + 3 < NN) *(float4*)&dst[n] = make_float4(o[0], o[1], o[2], o[3]);
    else {
#pragma unroll
      for (int j = 0; j < 4; ++j) if (n + j < NN) dst[n + j] = o[j];
    }
  }
}

__global__ void k_colnorm(const float* __restrict__ xf, float* __restrict__ icn) {
  __shared__ float sc[4];
  int bf = blockIdx.x;
  const float* rowp = xf + (size_t)bf * NN;
  float s = 0.f;
  for (int i = threadIdx.x; i < NN; i += 256) { float v = rowp[i]; s = fmaf(v, v, s); }
  s = wredSum(s);
  int lane = threadIdx.x & 63, w = threadIdx.x >> 6;
  if (lane == 0) sc[w] = s;
  __syncthreads();
  if (threadIdx.x == 0)
    icn[bf] = 1.f / fmaxf(sqrtf(sc[0] + sc[1] + sc[2] + sc[3]), 1e-12f);
}

__global__ void k_rownorm(const float* __restrict__ xf, const float* __restrict__ icn,
                          float* __restrict__ irn) {
  int b = blockIdx.y;
  int n = blockIdx.x * 256 + threadIdx.x;
  if (n >= NN) return;
  float s = 0.f;
  for (int f = 0; f < FLEN; ++f) {
    float v = xf[((size_t)b * FLEN + f) * NN + n] * icn[b * FLEN + f];
    s = fmaf(v, v, s);
  }
  irn[b * NN + n] = 1.f / fmaxf(sqrtf(s), 1e-12f);
}

__global__ void k_xe(const float* __restrict__ xf, const float* __restrict__ icn,
                     const float* __restrict__ irn, const float* __restrict__ Ex,
                     float* __restrict__ xe) {
  __shared__ __align__(16) float As[16][64];
  __shared__ __align__(16) float Bs[16][128];
  const int b = blockIdx.y;
  const int n0 = blockIdx.x * 64;
  const int tid = threadIdx.x;
  const int tn = tid >> 4, te = tid & 15;
  float acc[4][8] = {};
  for (int f0 = 0; f0 < 160; f0 += 16) {
    __syncthreads();
    {
      int kt = tid >> 4, q = tid & 15;
      int f = f0 + kt;
      int n = n0 + q * 4;
      float4 v = make_float4(0, 0, 0, 0);
      if (f < FLEN) {
        float ic = icn[b * FLEN + f];
        const float* src = &xf[((size_t)b * FLEN + f) * NN + n];
        if (n + 3 < NN) v = *(const float4*)src;
        else {
          if (n + 0 < NN) v.x = src[0];
          if (n + 1 < NN) v.y = src[1];
          if (n + 2 < NN) v.z = src[2];
          if (n + 3 < NN) v.w = src[3];
        }
        v.x *= ic; v.y *= ic; v.z *= ic; v.w *= ic;
      }
      *(float4*)&As[kt][q * 4] = v;
    }
    for (int l = tid; l < 512; l += 256) {
      int kt = l >> 5, q = l & 31;
      int f = f0 + kt;
      float4 v = make_float4(0, 0, 0, 0);
      if (f < FLEN) v = *(const float4*)&Ex[(size_t)f * EE + q * 4];
      *(float4*)&Bs[kt][q * 4] = v;
    }
    __syncthreads();
#pragma unroll
    for (int k = 0; k < 16; ++k) {
      float4 a  = *(float4*)&As[k][tn * 4];
      float4 b0 = *(float4*)&Bs[k][te * 4];
      float4 b1 = *(float4*)&Bs[k][64 + te * 4];
      float av[4] = {a.x, a.y, a.z, a.w};
      float bv[8] = {b0.x, b0.y, b0.z, b0.w, b1.x, b1.y, b1.z, b1.w};
#pragma unroll
      for (int i = 0; i < 4; ++i)
#pragma unroll
        for (int j = 0; j < 8; ++j)
          acc[i][j] = fmaf(av[i], bv[j], acc[i][j]);
    }
  }
#pragma unroll
  for (int i = 0; i < 4; ++i) {
    int n = n0 + tn * 4 + i;
    if (n >= NN) continue;
    float sc = irn[b * NN + n];
    float* dst = &xe[((size_t)b * NN + n) * EE];
    *(float4*)&dst[te * 4] =
        make_float4(acc[i][0] * sc, acc[i][1] * sc, acc[i][2] * sc, acc[i][3] * sc);
    *(float4*)&dst[64 + te * 4] =
        make_float4(acc[i][4] * sc, acc[i][5] * sc, acc[i][6] * sc, acc[i][7] * sc);
  }
}

// x1 = relu([xe|nodes] . Wd[n]); cooperative float4 Wd streaming.
// Also emits x1 hi/lo fp16 into the (dead after this kernel) xe region,
// interleaved per (b,n) slot: slot base ushort = (b*NN+n)*256; hi at +h, lo at +128+h.
__global__ void k_x1(const float* xe, const float* __restrict__ nodes,
                     const float* __restrict__ Wd, float* __restrict__ x1,
                     ushort_t* x1hl) {
  __shared__ __align__(16) float xk[8][DKK];
  __shared__ float red[4][32][33];
  const int n = blockIdx.x;
  const int tid = threadIdx.x;
  {
    int b = tid >> 5, q = tid & 31;
    *(float4*)&xk[b][q * 4] = *(const float4*)&xe[((size_t)b * NN + n) * EE + q * 4];
  }
  if (tid < 128) {
    int b = tid >> 4, i = tid & 15;
    xk[b][EE + i] = nodes[(size_t)n * IDD + i];
  }
  __syncthreads();
  const int h4 = tid & 31;
  const int dg = tid >> 5;
  float acc[8][4] = {};
  for (int d = dg; d < DKK; d += 8) {
    float4 wv = *(const float4*)&Wd[((size_t)n * DKK + d) * HH + h4 * 4];
#pragma unroll
    for (int b = 0; b < 8; ++b) {
      float xv = xk[b][d];
      acc[b][0] = fmaf(xv, wv.x, acc[b][0]);
      acc[b][1] = fmaf(xv, wv.y, acc[b][1]);
      acc[b][2] = fmaf(xv, wv.z, acc[b][2]);
      acc[b][3] = fmaf(xv, wv.w, acc[b][3]);
    }
  }
#pragma unroll
  for (int b = 0; b < 8; ++b)
#pragma unroll
    for (int j = 0; j < 4; ++j)
      acc[b][j] += __shfl_xor(acc[b][j], 32, 64);
  const int wv_ = tid >> 6, lane = tid & 63;
  if (lane < 32) {
#pragma unroll
    for (int b = 0; b < 8; ++b)
#pragma unroll
      for (int j = 0; j < 4; ++j)
        red[wv_][lane][b * 4 + j] = acc[b][j];
  }
  __syncthreads();
#pragma unroll
  for (int o = 0; o < 4; ++o) {
    int idx = tid + o * 256;
    int b = idx >> 7, h = idx & 127;
    float s = red[0][h >> 2][b * 4 + (h & 3)] + red[1][h >> 2][b * 4 + (h & 3)] +
              red[2][h >> 2][b * 4 + (h & 3)] + red[3][h >> 2][b * 4 + (h & 3)];
    s = fmaxf(s, 0.f);
    x1[((size_t)b * NN + n) * HH + h] = s;
    ushort_t hi, lo;
    split16(s, hi, lo);
    size_t base = ((size_t)b * NN + n) * 256;
    x1hl[base + h] = hi;
    x1hl[base + 128 + h] = lo;
  }
}

__global__ void k_ln_stats(const float* __restrict__ x1, float* __restrict__ lns) {
  __shared__ float sc[4], sc2[4];
  int b = blockIdx.y, chunk = blockIdx.x;
  const float* base = x1 + (size_t)b * NN * HH + (size_t)chunk * 8000;
  float s = 0.f, s2 = 0.f;
  for (int i = threadIdx.x; i < 8000; i += 256) {
    float v = base[i];
    s += v; s2 = fmaf(v, v, s2);
  }
  s = wredSum(s); s2 = wredSum(s2);
  int lane = threadIdx.x & 63, w = threadIdx.x >> 6;
  if (lane == 0) { sc[w] = s; sc2[w] = s2; }
  __syncthreads();
  if (threadIdx.x == 0) {
    atomicAdd(&lns[b], sc[0] + sc[1] + sc[2] + sc[3]);
    atomicAdd(&lns[8 + b], sc2[0] + sc2[1] + sc2[2] + sc2[3]);
  }
}

__global__ void k_ln_final(const float* __restrict__ lns, float* __restrict__ lnf) {
  int b = threadIdx.x;
  if (b < 8) {
    float cnt = (float)(NN * HH);
    float mu = lns[b] / cnt;
    float var = fmaxf(lns[8 + b] / cnt - mu * mu, 0.f);
    lnf[b] = mu;
    lnf[8 + b] = 1.f / sqrtf(var + 1e-8f);
  }
}

// adp = ((x1 . Wx) - mu*colsumW) * inv_sd, emitted directly as fp16 hi/lo
__global__ void k_adp(const float* __restrict__ x1, const float* __restrict__ Wx,
                      const float* __restrict__ csw, const float* __restrict__ lnf,
                      ushort_t* __restrict__ adphl) {
  __shared__ __align__(16) float As[16][64];
  __shared__ __align__(16) float Bs[16][128];
  const int r0 = blockIdx.x * 64;
  const int tid = threadIdx.x;
  const int tn = tid >> 4, te = tid & 15;
  float acc[4][8] = {};
  for (int k0 = 0; k0 < HH; k0 += 16) {
    __syncthreads();
    {
      int rr = tid >> 2, kq = tid & 3;
      float4 v = *(const float4*)&x1[(size_t)(r0 + rr) * HH + k0 + kq * 4];
      As[kq * 4 + 0][rr] = v.x;
      As[kq * 4 + 1][rr] = v.y;
      As[kq * 4 + 2][rr] = v.z;
      As[kq * 4 + 3][rr] = v.w;
    }
    for (int l = tid; l < 512; l += 256) {
      int kt = l >> 5, q = l & 31;
      *(float4*)&Bs[kt][q * 4] = *(const float4*)&Wx[(size_t)(k0 + kt) * HH + q * 4];
    }
    __syncthreads();
#pragma unroll
    for (int k = 0; k < 16; ++k) {
      float4 a  = *(float4*)&As[k][tn * 4];
      float4 b0 = *(float4*)&Bs[k][te * 4];
      float4 b1 = *(float4*)&Bs[k][64 + te * 4];
      float av[4] = {a.x, a.y, a.z, a.w};
      float bv[8] = {b0.x, b0.y, b0.z, b0.w, b1.x, b1.y, b1.z, b1.w};
#pragma unroll
      for (int i = 0; i < 4; ++i)
#pragma unroll
        for (int j = 0; j < 8; ++j)
          acc[i][j] = fmaf(av[i], bv[j], acc[i][j]);
    }
  }
  float4 c0 = *(const float4*)&csw[te * 4];
  float4 c1 = *(const float4*)&csw[64 + te * 4];
  float cw[8] = {c0.x, c0.y, c0.z, c0.w, c1.x, c1.y, c1.z, c1.w};
#pragma unroll
  for (int i = 0; i < 4; ++i) {
    int r = r0 + tn * 4 + i;
    int b = r / NN;
    float mu = lnf[b], isd = lnf[8 + b];
    size_t base = (size_t)r * 256;
    ushort_t hi[8], lo[8];
#pragma unroll
    for (int j = 0; j < 8; ++j) {
      float o = (acc[i][j] - mu * cw[j]) * isd;
      split16(o, hi[j], lo[j]);
    }
    ushort4 u;
    u.x = hi[0]; u.y = hi[1]; u.z = hi[2]; u.w = hi[3];
    *(ushort4*)&adphl[base + te * 4] = u;
    u.x = hi[4]; u.y = hi[5]; u.z = hi[6]; u.w = hi[7];
    *(ushort4*)&adphl[base + 64 + te * 4] = u;
    u.x = lo[0]; u.y = lo[1]; u.z = lo[2]; u.w = lo[3];
    *(ushort4*)&adphl[base + 128 + te * 4] = u;
    u.x = lo[4]; u.y = lo[5]; u.z = lo[6]; u.w = lo[7];
    *(ushort4*)&adphl[base + 128 + 64 + te * 4] = u;
  }
}

// ================= FUSED adj + topk-mask + softmax =================
// One block owns 16 output rows (n0..n0+15) of one batch b; the full
// 16 x 2000 relu(adj) strip lives in LDS, so the 128 MB adj intermediate
// never touches HBM and the output is written exactly once.
//
// Phase 1: adj = adp . x1^T via fp16-split MFMA (hi*hi + hi*lo + lo*hi).
//   A-frags (16 rows of adphl) are register-resident for the whole kernel;
//   B-frags load DIRECTLY from global (same 16B/lane pattern the old LDS
//   staging produced: frag row = lane&15, k = (lane>>4)*8). No barriers.
// Phase 2: one wave per row. topk-20:
//   cpos = #positives. cpos<=20 -> all positives kept (zero-ties harmless:
//   masked/unmasked zeros give identical softmax terms).
//   Else bracket candidates into [20,64] by threshold bisection (value-space
//   first, float-bit-space after: guaranteed to land in a width-45 window for
//   distinct floats), ballot-compact (val,idx) to LDS, bitonic-sort 64 via
//   shfl_xor (21 steps), t20 = rank-19 value. D = sum_top20 exp(v-m) + 1980*exp(-m).
__global__ __launch_bounds__(512, 1) void k_fused(
    const ushort_t* __restrict__ adphl, const ushort_t* __restrict__ x1hl,
    float* __restrict__ out) {
  extern __shared__ float smem[];
  float* cache = smem;                       // [16][CACHE_W]
  float* scrV = smem + 16 * CACHE_W;         // [8][64] candidate values
  int*   scrI = (int*)(scrV + 8 * 64);       // [8][64] candidate indices

  const int b = blockIdx.y;
  const int n0 = blockIdx.x * 16;
  const int tid = threadIdx.x;
  const int w = tid >> 6;        // wave 0..7
  const int lane = tid & 63;
  const int quad = lane >> 4, r16 = lane & 15;

  // ---- phase 1: GEMM into LDS row-cache ----
  half8 Ah[4], Al[4];
  {
    const ushort_t* abase =
        adphl + ((size_t)(b * NN + n0 + r16)) * 256 + quad * 8;
#pragma unroll
    for (int ks = 0; ks < 4; ++ks) {
      Ah[ks] = *(const half8*)(abase + ks * 32);
      Al[ks] = *(const half8*)(abase + 128 + ks * 32);
    }
  }
  for (int s = 0; s < 4; ++s) {
    const int mb = s * 512 + w * 64;
#pragma unroll
    for (int i = 0; i < 4; ++i) {
      const int mt = mb + i * 16 + r16;           // 0..2047
      const int mc = (mt < NN) ? mt : NN - 1;     // clamp loads; pad stored as -1
      const ushort_t* bbase =
          x1hl + ((size_t)(b * NN + mc)) * 256 + quad * 8;
      half8 Bh[4], Bl[4];
#pragma unroll
      for (int ks = 0; ks < 4; ++ks) {
        Bh[ks] = *(const half8*)(bbase + ks * 32);
        Bl[ks] = *(const half8*)(bbase + 128 + ks * 32);
      }
      f32x4 acc = (f32x4){0.f, 0.f, 0.f, 0.f};
#pragma unroll
      for (int ks = 0; ks < 4; ++ks) {
        acc = __builtin_amdgcn_mfma_f32_16x16x32_f16(Ah[ks], Bh[ks], acc, 0, 0, 0);
        acc = __builtin_amdgcn_mfma_f32_16x16x32_f16(Ah[ks], Bl[ks], acc, 0, 0, 0);
        acc = __builtin_amdgcn_mfma_f32_16x16x32_f16(Al[ks], Bh[ks], acc, 0, 0, 0);
      }
      // D layout: col = lane&15 -> m-tile col; row = quad*4+reg -> block row
#pragma unroll
      for (int reg = 0; reg < 4; ++reg) {
        int row = quad * 4 + reg;
        float v = (mt < NN) ? fmaxf(acc[reg], 0.f) : -1.f;
        cache[row * CACHE_W + mt] = v;
      }
    }
  }
  __syncthreads();

  // ---- phase 2: per-row topk + softmax, one wave per row, 2 rows/wave ----
  for (int rr = 0; rr < 2; ++rr) {
    const int row = w * 2 + rr;
    const float* crow = cache + row * CACHE_W;
    f32x4 V[8];   // lane's 32 values: m = j*256 + lane*4 + e
#pragma unroll
    for (int j = 0; j < 8; ++j)
      V[j] = *(const f32x4*)&crow[j * 256 + lane * 4];

    float mx = -1.f, cp = 0.f;
#pragma unroll
    for (int j = 0; j < 8; ++j)
#pragma unroll
      for (int e = 0; e < 4; ++e) {
        mx = fmaxf(mx, V[j][e]);
        cp += (V[j][e] > 0.f) ? 1.f : 0.f;
      }
    const float m = wredMaxAll(mx);     // >= 0 (relu)
    const float cpos = wredSumAll(cp);
    const float em = expf(-m);
    float* g = out + ((size_t)(b * NN + n0 + row)) * NN;

    if (cpos <= 20.5f) {
      // all positives are in the top-20; zero-ties give identical output
      float s = 0.f;
#pragma unroll
      for (int j = 0; j < 8; ++j)
#pragma unroll
        for (int e = 0; e < 4; ++e)
          if (V[j][e] > 0.f) s += expf(V[j][e] - m);
      s = wredSumAll(s);
      const float invD = 1.f / (s + (2000.f - cpos) * em);
      const float defv = em * invD;
#pragma unroll
      for (int j = 0; j < 8; ++j) {
        int m0 = j * 256 + lane * 4;
        if (m0 >= NN) continue;
        float4 o;
        o.x = (V[j][0] > 0.f) ? expf(V[j][0] - m) * invD : defv;
        o.y = (V[j][1] > 0.f) ? expf(V[j][1] - m) * invD : defv;
        o.z = (V[j][2] > 0.f) ? expf(V[j][2] - m) * invD : defv;
        o.w = (V[j][3] > 0.f) ? expf(V[j][3] - m) * invD : defv;
        *(float4*)&g[m0] = o;
      }
    } else {
      // bracket candidate count into [20,64]
      float tval = 0.f, cf = cpos;
      if (cpos > 64.5f) {
        float tlo = 0.f, thi = m;
        bool found = false;
        for (int it = 0; it < 64 && !found; ++it) {
          float mid = (it < 12)
              ? 0.5f * (tlo + thi)
              : __uint_as_float((__float_as_uint(tlo) + __float_as_uint(thi)) >> 1);
          float c = 0.f;
#pragma unroll
          for (int j = 0; j < 8; ++j)
#pragma unroll
            for (int e = 0; e < 4; ++e)
              c += (V[j][e] > mid) ? 1.f : 0.f;
          c = wredSumAll(c);
          if (c > 64.5f) tlo = mid;
          else if (c < 19.5f) thi = mid;
          else { tval = mid; cf = c; found = true; }
        }
        if (!found) { tval = tlo; cf = 64.f; }  // unreachable for distinct floats
      }
      int cI = (int)(cf + 0.5f);
      if (cI > 64) cI = 64;

      // ballot-compact candidates {v > tval} into per-wave LDS scratch
      float* sv = scrV + w * 64;
      int* si = scrI + w * 64;
      int base = 0;
#pragma unroll
      for (int j = 0; j < 8; ++j)
#pragma unroll
        for (int e = 0; e < 4; ++e) {
          bool p = V[j][e] > tval;
          unsigned long long msk = __ballot(p);
          if (p) {
            int pos = base + (int)__popcll(msk & ((1ull << lane) - 1ull));
            if (pos < 64) { sv[pos] = V[j][e]; si[pos] = j * 256 + lane * 4 + e; }
          }
          base += (int)__popcll(msk);
        }
      asm volatile("s_waitcnt lgkmcnt(0)" ::: "memory");

      float cv = (lane < cI) ? sv[lane] : -1.f;
      int ci = (lane < cI) ? si[lane] : 0x7fffffff;
      // bitonic sort, descending (ties -> lower index first)
#pragma unroll
      for (int k = 2; k <= 64; k <<= 1)
#pragma unroll
        for (int j = k >> 1; j > 0; j >>= 1) {
          float ov = __shfl_xor(cv, j, 64);
          int oi = __shfl_xor(ci, j, 64);
          bool otherBetter = (ov > cv) || (ov == cv && oi < ci);
          bool iAmLow = (lane & j) == 0;
          bool desc = (lane & k) == 0;
          bool take = (desc == iAmLow) ? otherBetter : !otherBetter;
          if (take) { cv = ov; ci = oi; }
        }
      const float t20 = __shfl(cv, 19, 64);   // 20th largest (cI >= 20)
      float e20 = (lane < 20) ? expf(cv - m) : 0.f;
      const float s20 = wredSumAll(e20);
      const float invD = 1.f / (s20 + (2000.f - 20.f) * em);
      const float defv = em * invD;
#pragma unroll
      for (int j = 0; j < 8; ++j) {
        int m0 = j * 256 + lane * 4;
        if (m0 >= NN) continue;
        float4 o;
        o.x = (V[j][0] >= t20) ? expf(V[j][0] - m) * invD : defv;
        o.y = (V[j][1] >= t20) ? expf(V[j][1] - m) * invD : defv;
        o.z = (V[j][2] >= t20) ? expf(V[j][2] - m) * invD : defv;
        o.w = (V[j][3] >= t20) ? expf(V[j][3] - m) * invD : defv;
        *(float4*)&g[m0] = o;
      }
    }
  }
}

extern "C" void kernel_launch(void* const* d_in, const int* in_sizes, int n_in,
                              void* d_out, int out_size, void* d_ws, size_t ws_size,
                              hipStream_t stream) {
  const float* x     = (const float*)d_in[0];
  const float* Ex    = (const float*)d_in[1];
  const float* nodes = (const float*)d_in[2];
  const float* Wd    = (const float*)d_in[3];
  const float* Wx    = (const float*)d_in[4];
  float* out = (float*)d_out;
  float* w = (float*)d_ws;
  float* tw  = w + OFF_TW;
  float* xf  = w + OFF_XF;
  float* icn = w + OFF_ICN;
  float* irn = w + OFF_IRN;
  float* xe  = w + OFF_XE;
  float* x1  = w + OFF_X1;
  float* csw = w + OFF_CSW;
  float* lns = w + OFF_LNS;
  float* lnf = w + OFF_LNF;
  ushort_t* adphl = (ushort_t*)(w + OFF_ADP);
  ushort_t* x1hl  = (ushort_t*)(w + OFF_XE);  // reuses dead xe region

  // opt in to >64KB dynamic LDS for the fused kernel (once; no-op if unneeded)
  static int _once = []() {
    (void)hipFuncSetAttribute((const void*)k_fused,
                              hipFuncAttributeMaxDynamicSharedMemorySize,
                              FUSED_LDS_BYTES);
    return 0;
  }();
  (void)_once;

  k_init<<<1, 128, 0, stream>>>(Wx, csw, lns);
  k_tw<<<(TT * FLEN + 255) / 256, 256, 0, stream>>>(tw);
  k_dft<<<dim3(16, 5, BB), 256, 0, stream>>>(x, tw, xf);
  k_colnorm<<<BB * FLEN, 256, 0, stream>>>(xf, icn);
  k_rownorm<<<dim3(8, BB), 256, 0, stream>>>(xf, icn, irn);
  k_xe<<<dim3(32, BB), 256, 0, stream>>>(xf, icn, irn, Ex, xe);
  k_x1<<<NN, 256, 0, stream>>>(xe, nodes, Wd, x1, x1hl);
  k_ln_stats<<<dim3(32, BB), 256, 0, stream>>>(x1, lns);
  k_ln_final<<<1, 64, 0, stream>>>(lns, lnf);
  k_adp<<<250, 256, 0, stream>>>(x1, Wx, csw, lnf, adphl);
  k_fused<<<dim3(125, BB), 512, FUSED_LDS_BYTES, stream>>>(adphl, x1hl, out);
}

// Round 2
// 571.475 us; speedup vs baseline: 1.0188x; 1.0188x over previous
//
#include <hip/hip_runtime.h>
#include <math.h>

#define BB 8
#define TT 288
#define NN 2000
#define FLEN 145
#define EE 128
#define IDD 16
#define HH 128
#define DKK 144
#define KTOP 20

typedef _Float16 half8 __attribute__((ext_vector_type(8)));
typedef float f32x4 __attribute__((ext_vector_type(4)));
typedef unsigned short ushort_t;

// ---- workspace layout (float offsets) ----
#define OFF_TW  ((size_t)0)
#define SZ_TW   ((size_t)TT*FLEN*2)
#define OFF_XF  (OFF_TW + SZ_TW)
#define SZ_XF   ((size_t)BB*FLEN*NN)
#define OFF_ICN (OFF_XF + SZ_XF)
#define OFF_IRN (OFF_ICN + (size_t)BB*FLEN)
#define OFF_XE  (OFF_IRN + (size_t)BB*NN)   // after k_x1 consumes xe, region is reused as x1 hi/lo fp16 (interleaved per-slot)
#define SZ_BNH  ((size_t)BB*NN*HH)
#define OFF_X1  (OFF_XE + SZ_BNH)
#define OFF_ADP (OFF_X1 + SZ_BNH)           // holds adp hi/lo fp16 (interleaved per-slot), never fp32
#define OFF_CSW (OFF_ADP + SZ_BNH)
#define OFF_LNS (OFF_CSW + HH)
#define OFF_LNF (OFF_LNS + 16)

// fused adj+softmax LDS: 16-row cache (stride 2064 floats -> max 2-way bank
// aliasing on stores/reads, free per m136) + per-wave topk scratch (16 waves)
#define CACHE_W 2064
#define FUSED_LDS_BYTES ((16 * CACHE_W + 2 * 16 * 64) * 4)

__device__ __forceinline__ float wredSum(float v) {
#pragma unroll
  for (int o = 32; o > 0; o >>= 1) v += __shfl_down(v, o, 64);
  return v;
}
__device__ __forceinline__ float wredMax(float v) {
#pragma unroll
  for (int o = 32; o > 0; o >>= 1) v = fmaxf(v, __shfl_down(v, o, 64));
  return v;
}
// butterfly variants: result valid in ALL lanes (no broadcast needed)
__device__ __forceinline__ float wredSumAll(float v) {
#pragma unroll
  for (int o = 32; o > 0; o >>= 1) v += __shfl_xor(v, o, 64);
  return v;
}
__device__ __forceinline__ float wredMaxAll(float v) {
#pragma unroll
  for (int o = 32; o > 0; o >>= 1) v = fmaxf(v, __shfl_xor(v, o, 64));
  return v;
}

// fp16 hi/lo split: v = hi + lo + O(2^-22 * v)
__device__ __forceinline__ void split16(float v, ushort_t& hi, ushort_t& lo) {
  _Float16 h = (_Float16)v;
  _Float16 l = (_Float16)(v - (float)h);
  union { _Float16 f; ushort_t u; } a, b;
  a.f = h; b.f = l;
  hi = a.u; lo = b.u;
}

// colsum of Wxabs + zero LN accumulators
__global__ void k_init(const float* __restrict__ Wx, float* __restrict__ csw,
                       float* __restrict__ lns) {
  int k = threadIdx.x;
  float s = 0.f;
  for (int h = 0; h < HH; ++h) s += Wx[h * HH + k];
  csw[k] = s;
  if (k < 16) lns[k] = 0.f;
}

// twiddles: exact int reduction of angle
__global__ void k_tw(float* __restrict__ tw) {
  int id = blockIdx.x * 256 + threadIdx.x;
  if (id >= TT * FLEN) return;
  int t = id / FLEN, f = id % FLEN;
  int r = (t * f) % TT;
  double th = -2.0 * 3.14159265358979323846 * (double)r / (double)TT;
  tw[2 * id]     = (float)cos(th);
  tw[2 * id + 1] = (float)sin(th);
}

// xf[b][f][n] = |rfft(x[b,:,n])[f]|
__global__ void k_dft(const float* __restrict__ x, const float* __restrict__ tw,
                      float* __restrict__ xf) {
  __shared__ __align__(16) float Xs[16][128];
  __shared__ __align__(16) float TWs[16][32][2];
  const int b = blockIdx.z;
  const int f0 = blockIdx.y * 32;
  const int n0 = blockIdx.x * 128;
  const int tid = threadIdx.x;
  const int tn = tid & 31;
  const int tf = tid >> 5;
  float ar[4][4] = {}, ai[4][4] = {};
  for (int t0 = 0; t0 < TT; t0 += 16) {
    __syncthreads();
    for (int l = tid; l < 512; l += 256) {
      int row = l >> 5, q = l & 31;
      int n = n0 + q * 4;
      const float* src = x + ((size_t)b * TT + (t0 + row)) * NN + n;
      float4 v = make_float4(0, 0, 0, 0);
      if (n + 3 < NN) v = *(const float4*)src;
      else {
        if (n + 0 < NN) v.x = src[0];
        if (n + 1 < NN) v.y = src[1];
        if (n + 2 < NN) v.z = src[2];
        if (n + 3 < NN) v.w = src[3];
      }
      *(float4*)&Xs[row][q * 4] = v;
    }
    for (int l = tid; l < 512; l += 256) {
      int row = l >> 5, ff = l & 31;
      int f = f0 + ff;
      float2 cs = make_float2(0, 0);
      if (f < FLEN) cs = *(const float2*)&tw[((size_t)(t0 + row) * FLEN + f) * 2];
      *(float2*)&TWs[row][ff][0] = cs;
    }
    __syncthreads();
#pragma unroll 4
    for (int t = 0; t < 16; ++t) {
      float4 xv = *(float4*)&Xs[t][tn * 4];
      float xx[4] = {xv.x, xv.y, xv.z, xv.w};
      float4 p0 = *(float4*)&TWs[t][tf * 4][0];
      float4 p1 = *(float4*)&TWs[t][tf * 4 + 2][0];
      float c[4] = {p0.x, p0.z, p1.x, p1.z};
      float s[4] = {p0.y, p0.w, p1.y, p1.w};
#pragma unroll
      for (int i = 0; i < 4; ++i)
#pragma unroll
        for (int j = 0; j < 4; ++j) {
          ar[i][j] = fmaf(xx[j], c[i], ar[i][j]);
          ai[i][j] = fmaf(xx[j], s[i], ai[i][j]);
        }
    }
  }
#pragma unroll
  for (int i = 0; i < 4; ++i) {
    int f = f0 + tf * 4 + i;
    if (f >= FLEN) continue;
    float* dst = &xf[((size_t)b * FLEN + f) * NN];
    float o[4];
#pragma unroll
    for (int j = 0; j < 4; ++j)
      o[j] = sqrtf(ar[i][j] * ar[i][j] + ai[i][j] * ai[i][j]);
    int n = n0 + tn * 4;
    if (n + 3 < NN) *(float4*)&dst[n] = make_float4(o[0], o[1], o[2], o[3]);
    else {
#pragma unroll
      for (int j = 0; j < 4; ++j) if (n + j < NN) dst[n + j] = o[j];
    }
  }
}

__global__ void k_colnorm(const float* __restrict__ xf, float* __restrict__ icn) {
  __shared__ float sc[4];
  int bf = blockIdx.x;
  const float* rowp = xf + (size_t)bf * NN;
  float s = 0.f;
  for (int i = threadIdx.x; i < NN; i += 256) { float v = rowp[i]; s = fmaf(v, v, s); }
  s = wredSum(s);
  int lane = threadIdx.x & 63, w = threadIdx.x >> 6;
  if (lane == 0) sc[w] = s;
  __syncthreads();
  if (threadIdx.x == 0)
    icn[bf] = 1.f / fmaxf(sqrtf(sc[0] + sc[1] + sc[2] + sc[3]), 1e-12f);
}

__global__ void k_rownorm(const float* __restrict__ xf, const float* __restrict__ icn,
                          float* __restrict__ irn) {
  int b = blockIdx.y;
  int n = blockIdx.x * 256 + threadIdx.x;
  if (n >= NN) return;
  float s = 0.f;
  for (int f = 0; f < FLEN; ++f) {
    float v = xf[((size_t)b * FLEN + f) * NN + n] * icn[b * FLEN + f];
    s = fmaf(v, v, s);
  }
  irn[b * NN + n] = 1.f / fmaxf(sqrtf(s), 1e-12f);
}

__global__ void k_xe(const float* __restrict__ xf, const float* __restrict__ icn,
                     const float* __restrict__ irn, const float* __restrict__ Ex,
                     float* __restrict__ xe) {
  __shared__ __align__(16) float As[16][64];
  __shared__ __align__(16) float Bs[16][128];
  const int b = blockIdx.y;
  const int n0 = blockIdx.x * 64;
  const int tid = threadIdx.x;
  const int tn = tid >> 4, te = tid & 15;
  float acc[4][8] = {};
  for (int f0 = 0; f0 < 160; f0 += 16) {
    __syncthreads();
    {
      int kt = tid >> 4, q = tid & 15;
      int f = f0 + kt;
      int n = n0 + q * 4;
      float4 v = make_float4(0, 0, 0, 0);
      if (f < FLEN) {
        float ic = icn[b * FLEN + f];
        const float* src = &xf[((size_t)b * FLEN + f) * NN + n];
        if (n + 3 < NN) v = *(const float4*)src;
        else {
          if (n + 0 < NN) v.x = src[0];
          if (n + 1 < NN) v.y = src[1];
          if (n + 2 < NN) v.z = src[2];
          if (n + 3 < NN) v.w = src[3];
        }
        v.x *= ic; v.y *= ic; v.z *= ic; v.w *= ic;
      }
      *(float4*)&As[kt][q * 4] = v;
    }
    for (int l = tid; l < 512; l += 256) {
      int kt = l >> 5, q = l & 31;
      int f = f0 + kt;
      float4 v = make_float4(0, 0, 0, 0);
      if (f < FLEN) v = *(const float4*)&Ex[(size_t)f * EE + q * 4];
      *(float4*)&Bs[kt][q * 4] = v;
    }
    __syncthreads();
#pragma unroll
    for (int k = 0; k < 16; ++k) {
      float4 a  = *(float4*)&As[k][tn * 4];
      float4 b0 = *(float4*)&Bs[k][te * 4];
      float4 b1 = *(float4*)&Bs[k][64 + te * 4];
      float av[4] = {a.x, a.y, a.z, a.w};
      float bv[8] = {b0.x, b0.y, b0.z, b0.w, b1.x, b1.y, b1.z, b1.w};
#pragma unroll
      for (int i = 0; i < 4; ++i)
#pragma unroll
        for (int j = 0; j < 8; ++j)
          acc[i][j] = fmaf(av[i], bv[j], acc[i][j]);
    }
  }
#pragma unroll
  for (int i = 0; i < 4; ++i) {
    int n = n0 + tn * 4 + i;
    if (n >= NN) continue;
    float sc = irn[b * NN + n];
    float* dst = &xe[((size_t)b * NN + n) * EE];
    *(float4*)&dst[te * 4] =
        make_float4(acc[i][0] * sc, acc[i][1] * sc, acc[i][2] * sc, acc[i][3] * sc);
    *(float4*)&dst[64 + te * 4] =
        make_float4(acc[i][4] * sc, acc[i][5] * sc, acc[i][6] * sc, acc[i][7] * sc);
  }
}

// x1 = relu([xe|nodes] . Wd[n]); cooperative float4 Wd streaming.
// Also emits x1 hi/lo fp16 into the (dead after this kernel) xe region,
// interleaved per (b,n) slot: slot base ushort = (b*NN+n)*256; hi at +h, lo at +128+h.
__global__ void k_x1(const float* xe, const float* __restrict__ nodes,
                     const float* __restrict__ Wd, float* __restrict__ x1,
                     ushort_t* x1hl) {
  __shared__ __align__(16) float xk[8][DKK];
  __shared__ float red[4][32][33];
  const int n = blockIdx.x;
  const int tid = threadIdx.x;
  {
    int b = tid >> 5, q = tid & 31;
    *(float4*)&xk[b][q * 4] = *(const float4*)&xe[((size_t)b * NN + n) * EE + q * 4];
  }
  if (tid < 128) {
    int b = tid >> 4, i = tid & 15;
    xk[b][EE + i] = nodes[(size_t)n * IDD + i];
  }
  __syncthreads();
  const int h4 = tid & 31;
  const int dg = tid >> 5;
  float acc[8][4] = {};
  for (int d = dg; d < DKK; d += 8) {
    float4 wv = *(const float4*)&Wd[((size_t)n * DKK + d) * HH + h4 * 4];
#pragma unroll
    for (int b = 0; b < 8; ++b) {
      float xv = xk[b][d];
      acc[b][0] = fmaf(xv, wv.x, acc[b][0]);
      acc[b][1] = fmaf(xv, wv.y, acc[b][1]);
      acc[b][2] = fmaf(xv, wv.z, acc[b][2]);
      acc[b][3] = fmaf(xv, wv.w, acc[b][3]);
    }
  }
#pragma unroll
  for (int b = 0; b < 8; ++b)
#pragma unroll
    for (int j = 0; j < 4; ++j)
      acc[b][j] += __shfl_xor(acc[b][j], 32, 64);
  const int wv_ = tid >> 6, lane = tid & 63;
  if (lane < 32) {
#pragma unroll
    for (int b = 0; b < 8; ++b)
#pragma unroll
      for (int j = 0; j < 4; ++j)
        red[wv_][lane][b * 4 + j] = acc[b][j];
  }
  __syncthreads();
#pragma unroll
  for (int o = 0; o < 4; ++o) {
    int idx = tid + o * 256;
    int b = idx >> 7, h = idx & 127;
    float s = red[0][h >> 2][b * 4 + (h & 3)] + red[1][h >> 2][b * 4 + (h & 3)] +
              red[2][h >> 2][b * 4 + (h & 3)] + red[3][h >> 2][b * 4 + (h & 3)];
    s = fmaxf(s, 0.f);
    x1[((size_t)b * NN + n) * HH + h] = s;
    ushort_t hi, lo;
    split16(s, hi, lo);
    size_t base = ((size_t)b * NN + n) * 256;
    x1hl[base + h] = hi;
    x1hl[base + 128 + h] = lo;
  }
}

__global__ void k_ln_stats(const float* __restrict__ x1, float* __restrict__ lns) {
  __shared__ float sc[4], sc2[4];
  int b = blockIdx.y, chunk = blockIdx.x;
  const float* base = x1 + (size_t)b * NN * HH + (size_t)chunk * 8000;
  float s = 0.f, s2 = 0.f;
  for (int i = threadIdx.x; i < 8000; i += 256) {
    float v = base[i];
    s += v; s2 = fmaf(v, v, s2);
  }
  s = wredSum(s); s2 = wredSum(s2);
  int lane = threadIdx.x & 63, w = threadIdx.x >> 6;
  if (lane == 0) { sc[w] = s; sc2[w] = s2; }
  __syncthreads();
  if (threadIdx.x == 0) {
    atomicAdd(&lns[b], sc[0] + sc[1] + sc[2] + sc[3]);
    atomicAdd(&lns[8 + b], sc2[0] + sc2[1] + sc2[2] + sc2[3]);
  }
}

__global__ void k_ln_final(const float* __restrict__ lns, float* __restrict__ lnf) {
  int b = threadIdx.x;
  if (b < 8) {
    float cnt = (float)(NN * HH);
    float mu = lns[b] / cnt;
    float var = fmaxf(lns[8 + b] / cnt - mu * mu, 0.f);
    lnf[b] = mu;
    lnf[8 + b] = 1.f / sqrtf(var + 1e-8f);
  }
}

// adp = ((x1 . Wx) - mu*colsumW) * inv_sd, emitted directly as fp16 hi/lo
__global__ void k_adp(const float* __restrict__ x1, const float* __restrict__ Wx,
                      const float* __restrict__ csw, const float* __restrict__ lnf,
                      ushort_t* __restrict__ adphl) {
  __shared__ __align__(16) float As[16][64];
  __shared__ __align__(16) float Bs[16][128];
  const int r0 = blockIdx.x * 64;
  const int tid = threadIdx.x;
  const int tn = tid >> 4, te = tid & 15;
  float acc[4][8] = {};
  for (int k0 = 0; k0 < HH; k0 += 16) {
    __syncthreads();
    {
      int rr = tid >> 2, kq = tid & 3;
      float4 v = *(const float4*)&x1[(size_t)(r0 + rr) * HH + k0 + kq * 4];
      As[kq * 4 + 0][rr] = v.x;
      As[kq * 4 + 1][rr] = v.y;
      As[kq * 4 + 2][rr] = v.z;
      As[kq * 4 + 3][rr] = v.w;
    }
    for (int l = tid; l < 512; l += 256) {
      int kt = l >> 5, q = l & 31;
      *(float4*)&Bs[kt][q * 4] = *(const float4*)&Wx[(size_t)(k0 + kt) * HH + q * 4];
    }
    __syncthreads();
#pragma unroll
    for (int k = 0; k < 16; ++k) {
      float4 a  = *(float4*)&As[k][tn * 4];
      float4 b0 = *(float4*)&Bs[k][te * 4];
      float4 b1 = *(float4*)&Bs[k][64 + te * 4];
      float av[4] = {a.x, a.y, a.z, a.w};
      float bv[8] = {b0.x, b0.y, b0.z, b0.w, b1.x, b1.y, b1.z, b1.w};
#pragma unroll
      for (int i = 0; i < 4; ++i)
#pragma unroll
        for (int j = 0; j < 8; ++j)
          acc[i][j] = fmaf(av[i], bv[j], acc[i][j]);
    }
  }
  float4 c0 = *(const float4*)&csw[te * 4];
  float4 c1 = *(const float4*)&csw[64 + te * 4];
  float cw[8] = {c0.x, c0.y, c0.z, c0.w, c1.x, c1.y, c1.z, c1.w};
#pragma unroll
  for (int i = 0; i < 4; ++i) {
    int r = r0 + tn * 4 + i;
    int b = r / NN;
    float mu = lnf[b], isd = lnf[8 + b];
    size_t base = (size_t)r * 256;
    ushort_t hi[8], lo[8];
#pragma unroll
    for (int j = 0; j < 8; ++j) {
      float o = (acc[i][j] - mu * cw[j]) * isd;
      split16(o, hi[j], lo[j]);
    }
    ushort4 u;
    u.x = hi[0]; u.y = hi[1]; u.z = hi[2]; u.w = hi[3];
    *(ushort4*)&adphl[base + te * 4] = u;
    u.x = hi[4]; u.y = hi[5]; u.z = hi[6]; u.w = hi[7];
    *(ushort4*)&adphl[base + 64 + te * 4] = u;
    u.x = lo[0]; u.y = lo[1]; u.z = lo[2]; u.w = lo[3];
    *(ushort4*)&adphl[base + 128 + te * 4] = u;
    u.x = lo[4]; u.y = lo[5]; u.z = lo[6]; u.w = lo[7];
    *(ushort4*)&adphl[base + 128 + 64 + te * 4] = u;
  }
}

// ================= FUSED adj + topk-mask + softmax =================
// One block (1024 threads, 16 waves) owns 16 output rows of one batch b; the
// full 16 x 2000 relu(adj) strip lives in LDS. 16 waves -> 4 waves/SIMD for
// latency hiding (v1 had 8 waves -> 2/SIMD and stalled at 21% occupancy).
//
// Phase 1: adj = adp . x1^T via fp16-split MFMA (hi*hi + hi*lo + lo*hi, single
//   acc chain -- accumulation order kept BIT-IDENTICAL to v1/k_adj since
//   absmax sits at the tolerance). Each wave covers 128 m (8 subtiles);
//   B-fragments are register-double-buffered: loads for subtile i+1 issue
//   before the MFMAs of subtile i (all indices compile-time, full unroll).
// Phase 2: one wave per row. topk-20 via positive-count -> threshold bisection
//   into [20,64] candidates -> ballot-compact -> 64-wide bitonic sort -> t20.
__global__ __launch_bounds__(1024, 1) void k_fused(
    const ushort_t* __restrict__ adphl, const ushort_t* __restrict__ x1hl,
    float* __restrict__ out) {
  extern __shared__ float smem[];
  float* cache = smem;                       // [16][CACHE_W]
  float* scrV = smem + 16 * CACHE_W;         // [16][64] candidate values
  int*   scrI = (int*)(scrV + 16 * 64);      // [16][64] candidate indices

  const int b = blockIdx.y;
  const int n0 = blockIdx.x * 16;
  const int tid = threadIdx.x;
  const int w = tid >> 6;        // wave 0..15
  const int lane = tid & 63;
  const int quad = lane >> 4, r16 = lane & 15;

  // ---- phase 1: GEMM into LDS row-cache ----
  half8 Ah[4], Al[4];
  {
    const ushort_t* abase =
        adphl + ((size_t)(b * NN + n0 + r16)) * 256 + quad * 8;
#pragma unroll
    for (int ks = 0; ks < 4; ++ks) {
      Ah[ks] = *(const half8*)(abase + ks * 32);
      Al[ks] = *(const half8*)(abase + 128 + ks * 32);
    }
  }
  const int mbase = w * 128;     // wave's m-range: 128 wide, 8 subtiles

  half8 Bh0[4], Bl0[4], Bh1[4], Bl1[4];

#define LOADB(I, BH, BL)                                                      \
  {                                                                           \
    int mt_ = mbase + (I) * 16 + r16;                                         \
    int mc_ = (mt_ < NN) ? mt_ : NN - 1;                                      \
    const ushort_t* bb_ = x1hl + ((size_t)(b * NN + mc_)) * 256 + quad * 8;   \
    BH[0] = *(const half8*)(bb_);       BL[0] = *(const half8*)(bb_ + 128);   \
    BH[1] = *(const half8*)(bb_ + 32);  BL[1] = *(const half8*)(bb_ + 160);   \
    BH[2] = *(const half8*)(bb_ + 64);  BL[2] = *(const half8*)(bb_ + 192);   \
    BH[3] = *(const half8*)(bb_ + 96);  BL[3] = *(const half8*)(bb_ + 224);   \
  }

#define STEP(I, BH, BL, BH2, BL2)                                             \
  {                                                                           \
    if ((I) < 7) LOADB((I) + 1, BH2, BL2);                                    \
    f32x4 acc = (f32x4){0.f, 0.f, 0.f, 0.f};                                  \
    _Pragma("unroll")                                                         \
    for (int ks = 0; ks < 4; ++ks) {                                          \
      acc = __builtin_amdgcn_mfma_f32_16x16x32_f16(Ah[ks], BH[ks], acc, 0, 0, 0); \
      acc = __builtin_amdgcn_mfma_f32_16x16x32_f16(Ah[ks], BL[ks], acc, 0, 0, 0); \
      acc = __builtin_amdgcn_mfma_f32_16x16x32_f16(Al[ks], BH[ks], acc, 0, 0, 0); \
    }                                                                         \
    int mt_ = mbase + (I) * 16 + r16;                                         \
    _Pragma("unroll")                                                         \
    for (int reg = 0; reg < 4; ++reg) {                                       \
      int row_ = quad * 4 + reg;                                              \
      float v_ = (mt_ < NN) ? fmaxf(acc[reg], 0.f) : -1.f;                    \
      cache[row_ * CACHE_W + mt_] = v_;                                       \
    }                                                                         \
  }

  LOADB(0, Bh0, Bl0);
  STEP(0, Bh0, Bl0, Bh1, Bl1);
  STEP(1, Bh1, Bl1, Bh0, Bl0);
  STEP(2, Bh0, Bl0, Bh1, Bl1);
  STEP(3, Bh1, Bl1, Bh0, Bl0);
  STEP(4, Bh0, Bl0, Bh1, Bl1);
  STEP(5, Bh1, Bl1, Bh0, Bl0);
  STEP(6, Bh0, Bl0, Bh1, Bl1);
  STEP(7, Bh1, Bl1, Bh0, Bl0);
#undef STEP
#undef LOADB

  __syncthreads();

  // ---- phase 2: per-row topk + softmax, one wave per row ----
  {
    const int row = w;
    const float* crow = cache + row * CACHE_W;
    f32x4 V[8];   // lane's 32 values: m = j*256 + lane*4 + e
#pragma unroll
    for (int j = 0; j < 8; ++j)
      V[j] = *(const f32x4*)&crow[j * 256 + lane * 4];

    float mx = -1.f, cp = 0.f;
#pragma unroll
    for (int j = 0; j < 8; ++j)
#pragma unroll
      for (int e = 0; e < 4; ++e) {
        mx = fmaxf(mx, V[j][e]);
        cp += (V[j][e] > 0.f) ? 1.f : 0.f;
      }
    const float m = wredMaxAll(mx);     // >= 0 (relu)
    const float cpos = wredSumAll(cp);
    const float em = expf(-m);
    float* g = out + ((size_t)(b * NN + n0 + row)) * NN;

    if (cpos <= 20.5f) {
      // all positives are in the top-20; zero-ties give identical output
      float s = 0.f;
#pragma unroll
      for (int j = 0; j < 8; ++j)
#pragma unroll
        for (int e = 0; e < 4; ++e)
          if (V[j][e] > 0.f) s += expf(V[j][e] - m);
      s = wredSumAll(s);
      const float invD = 1.f / (s + (2000.f - cpos) * em);
      const float defv = em * invD;
#pragma unroll
      for (int j = 0; j < 8; ++j) {
        int m0 = j * 256 + lane * 4;
        if (m0 >= NN) continue;
        float4 o;
        o.x = (V[j][0] > 0.f) ? expf(V[j][0] - m) * invD : defv;
        o.y = (V[j][1] > 0.f) ? expf(V[j][1] - m) * invD : defv;
        o.z = (V[j][2] > 0.f) ? expf(V[j][2] - m) * invD : defv;
        o.w = (V[j][3] > 0.f) ? expf(V[j][3] - m) * invD : defv;
        *(float4*)&g[m0] = o;
      }
    } else {
      // bracket candidate count into [20,64]
      float tval = 0.f, cf = cpos;
      if (cpos > 64.5f) {
        float tlo = 0.f, thi = m;
        bool found = false;
        for (int it = 0; it < 64 && !found; ++it) {
          float mid = (it < 12)
              ? 0.5f * (tlo + thi)
              : __uint_as_float((__float_as_uint(tlo) + __float_as_uint(thi)) >> 1);
          float c = 0.f;
#pragma unroll
          for (int j = 0; j < 8; ++j)
#pragma unroll
            for (int e = 0; e < 4; ++e)
              c += (V[j][e] > mid) ? 1.f : 0.f;
          c = wredSumAll(c);
          if (c > 64.5f) tlo = mid;
          else if (c < 19.5f) thi = mid;
          else { tval = mid; cf = c; found = true; }
        }
        if (!found) { tval = tlo; cf = 64.f; }  // unreachable for distinct floats
      }
      int cI = (int)(cf + 0.5f);
      if (cI > 64) cI = 64;

      // ballot-compact candidates {v > tval} into per-wave LDS scratch
      float* sv = scrV + w * 64;
      int* si = scrI + w * 64;
      int base = 0;
#pragma unroll
      for (int j = 0; j < 8; ++j)
#pragma unroll
        for (int e = 0; e < 4; ++e) {
          bool p = V[j][e] > tval;
          unsigned long long msk = __ballot(p);
          if (p) {
            int pos = base + (int)__popcll(msk & ((1ull << lane) - 1ull));
            if (pos < 64) { sv[pos] = V[j][e]; si[pos] = j * 256 + lane * 4 + e; }
          }
          base += (int)__popcll(msk);
        }
      asm volatile("s_waitcnt lgkmcnt(0)" ::: "memory");

      float cv = (lane < cI) ? sv[lane] : -1.f;
      int ci = (lane < cI) ? si[lane] : 0x7fffffff;
      // bitonic sort, descending (ties -> lower index first)
#pragma unroll
      for (int k = 2; k <= 64; k <<= 1)
#pragma unroll
        for (int j = k >> 1; j > 0; j >>= 1) {
          float ov = __shfl_xor(cv, j, 64);
          int oi = __shfl_xor(ci, j, 64);
          bool otherBetter = (ov > cv) || (ov == cv && oi < ci);
          bool iAmLow = (lane & j) == 0;
          bool desc = (lane & k) == 0;
          bool take = (desc == iAmLow) ? otherBetter : !otherBetter;
          if (take) { cv = ov; ci = oi; }
        }
      const float t20 = __shfl(cv, 19, 64);   // 20th largest (cI >= 20)
      float e20 = (lane < 20) ? expf(cv - m) : 0.f;
      const float s20 = wredSumAll(e20);
      const float invD = 1.f / (s20 + (2000.f - 20.f) * em);
      const float defv = em * invD;
#pragma unroll
      for (int j = 0; j < 8; ++j) {
        int m0 = j * 256 + lane * 4;
        if (m0 >= NN) continue;
        float4 o;
        o.x = (V[j][0] >= t20) ? expf(V[j][0] - m) * invD : defv;
        o.y = (V[j][1] >= t20) ? expf(V[j][1] - m) * invD : defv;
        o.z = (V[j][2] >= t20) ? expf(V[j][2] - m) * invD : defv;
        o.w = (V[j][3] >= t20) ? expf(V[j][3] - m) * invD : defv;
        *(float4*)&g[m0] = o;
      }
    }
  }
}

extern "C" void kernel_launch(void* const* d_in, const int* in_sizes, int n_in,
                              void* d_out, int out_size, void* d_ws, size_t ws_size,
                              hipStream_t stream) {
  const float* x     = (const float*)d_in[0];
  const float* Ex    = (const float*)d_in[1];
  const float* nodes = (const float*)d_in[2];
  const float* Wd    = (const float*)d_in[3];
  const float* Wx    = (const float*)d_in[4];
  float* out = (float*)d_out;
  float* w = (float*)d_ws;
  float* tw  = w + OFF_TW;
  float* xf  = w + OFF_XF;
  float* icn = w + OFF_ICN;
  float* irn = w + OFF_IRN;
  float* xe  = w + OFF_XE;
  float* x1  = w + OFF_X1;
  float* csw = w + OFF_CSW;
  float* lns = w + OFF_LNS;
  float* lnf = w + OFF_LNF;
  ushort_t* adphl = (ushort_t*)(w + OFF_ADP);
  ushort_t* x1hl  = (ushort_t*)(w + OFF_XE);  // reuses dead xe region

  // opt in to >64KB dynamic LDS for the fused kernel (once; no-op if unneeded)
  static int _once = []() {
    (void)hipFuncSetAttribute((const void*)k_fused,
                              hipFuncAttributeMaxDynamicSharedMemorySize,
                              FUSED_LDS_BYTES);
    return 0;
  }();
  (void)_once;

  k_init<<<1, 128, 0, stream>>>(Wx, csw, lns);
  k_tw<<<(TT * FLEN + 255) / 256, 256, 0, stream>>>(tw);
  k_dft<<<dim3(16, 5, BB), 256, 0, stream>>>(x, tw, xf);
  k_colnorm<<<BB * FLEN, 256, 0, stream>>>(xf, icn);
  k_rownorm<<<dim3(8, BB), 256, 0, stream>>>(xf, icn, irn);
  k_xe<<<dim3(32, BB), 256, 0, stream>>>(xf, icn, irn, Ex, xe);
  k_x1<<<NN, 256, 0, stream>>>(xe, nodes, Wd, x1, x1hl);
  k_ln_stats<<<dim3(32, BB), 256, 0, stream>>>(x1, lns);
  k_ln_final<<<1, 64, 0, stream>>>(lns, lnf);
  k_adp<<<250, 256, 0, stream>>>(x1, Wx, csw, lnf, adphl);
  k_fused<<<dim3(125, BB), 1024, FUSED_LDS_BYTES, stream>>>(adphl, x1hl, out);
}

// Round 4
// 571.222 us; speedup vs baseline: 1.0193x; 1.0004x over previous
//
#include <hip/hip_runtime.h>
#include <math.h>

#define BB 8
#define TT 288
#define NN 2000
#define FLEN 145
#define EE 128
#define IDD 16
#define HH 128
#define DKK 144
#define KTOP 20

typedef _Float16 half8 __attribute__((ext_vector_type(8)));
typedef float f32x4 __attribute__((ext_vector_type(4)));
typedef unsigned short ushort_t;

// ---- workspace layout (float offsets) ----
#define OFF_TW  ((size_t)0)
#define SZ_TW   ((size_t)TT*FLEN*2)
#define OFF_XF  (OFF_TW + SZ_TW)
#define SZ_XF   ((size_t)BB*FLEN*NN)
#define OFF_ICN (OFF_XF + SZ_XF)
#define OFF_IRN (OFF_ICN + (size_t)BB*FLEN)
#define OFF_XE  (OFF_IRN + (size_t)BB*NN)   // after k_x1 consumes xe, region is reused as x1 hi/lo fp16 (interleaved per-slot)
#define SZ_BNH  ((size_t)BB*NN*HH)
#define OFF_X1  (OFF_XE + SZ_BNH)
#define OFF_ADP (OFF_X1 + SZ_BNH)           // holds adp hi/lo fp16 (interleaved per-slot), never fp32
#define OFF_CSW (OFF_ADP + SZ_BNH)
#define OFF_LNS (OFF_CSW + HH)
#define OFF_LNF (OFF_LNS + 16)

__device__ __forceinline__ float wredSum(float v) {
#pragma unroll
  for (int o = 32; o > 0; o >>= 1) v += __shfl_down(v, o, 64);
  return v;
}
__device__ __forceinline__ float wredMax(float v) {
#pragma unroll
  for (int o = 32; o > 0; o >>= 1) v = fmaxf(v, __shfl_down(v, o, 64));
  return v;
}
// butterfly variants: result valid in ALL lanes (no broadcast needed)
__device__ __forceinline__ float wredSumAll(float v) {
#pragma unroll
  for (int o = 32; o > 0; o >>= 1) v += __shfl_xor(v, o, 64);
  return v;
}
__device__ __forceinline__ float wredMaxAll(float v) {
#pragma unroll
  for (int o = 32; o > 0; o >>= 1) v = fmaxf(v, __shfl_xor(v, o, 64));
  return v;
}

// fp16 hi/lo split: v = hi + lo + O(2^-22 * v)
__device__ __forceinline__ void split16(float v, ushort_t& hi, ushort_t& lo) {
  _Float16 h = (_Float16)v;
  _Float16 l = (_Float16)(v - (float)h);
  union { _Float16 f; ushort_t u; } a, b;
  a.f = h; b.f = l;
  hi = a.u; lo = b.u;
}

// colsum of Wxabs + zero LN accumulators
__global__ void k_init(const float* __restrict__ Wx, float* __restrict__ csw,
                       float* __restrict__ lns) {
  int k = threadIdx.x;
  float s = 0.f;
  for (int h = 0; h < HH; ++h) s += Wx[h * HH + k];
  csw[k] = s;
  if (k < 16) lns[k] = 0.f;
}

// twiddles: exact int reduction of angle
__global__ void k_tw(float* __restrict__ tw) {
  int id = blockIdx.x * 256 + threadIdx.x;
  if (id >= TT * FLEN) return;
  int t = id / FLEN, f = id % FLEN;
  int r = (t * f) % TT;
  double th = -2.0 * 3.14159265358979323846 * (double)r / (double)TT;
  tw[2 * id]     = (float)cos(th);
  tw[2 * id + 1] = (float)sin(th);
}

// xf[b][f][n] = |rfft(x[b,:,n])[f]|
__global__ void k_dft(const float* __restrict__ x, const float* __restrict__ tw,
                      float* __restrict__ xf) {
  __shared__ __align__(16) float Xs[16][128];
  __shared__ __align__(16) float TWs[16][32][2];
  const int b = blockIdx.z;
  const int f0 = blockIdx.y * 32;
  const int n0 = blockIdx.x * 128;
  const int tid = threadIdx.x;
  const int tn = tid & 31;
  const int tf = tid >> 5;
  float ar[4][4] = {}, ai[4][4] = {};
  for (int t0 = 0; t0 < TT; t0 += 16) {
    __syncthreads();
    for (int l = tid; l < 512; l += 256) {
      int row = l >> 5, q = l & 31;
      int n = n0 + q * 4;
      const float* src = x + ((size_t)b * TT + (t0 + row)) * NN + n;
      float4 v = make_float4(0, 0, 0, 0);
      if (n + 3 < NN) v = *(const float4*)src;
      else {
        if (n + 0 < NN) v.x = src[0];
        if (n + 1 < NN) v.y = src[1];
        if (n + 2 < NN) v.z = src[2];
        if (n + 3 < NN) v.w = src[3];
      }
      *(float4*)&Xs[row][q * 4] = v;
    }
    for (int l = tid; l < 512; l += 256) {
      int row = l >> 5, ff = l & 31;
      int f = f0 + ff;
      float2 cs = make_float2(0, 0);
      if (f < FLEN) cs = *(const float2*)&tw[((size_t)(t0 + row) * FLEN + f) * 2];
      *(float2*)&TWs[row][ff][0] = cs;
    }
    __syncthreads();
#pragma unroll 4
    for (int t = 0; t < 16; ++t) {
      float4 xv = *(float4*)&Xs[t][tn * 4];
      float xx[4] = {xv.x, xv.y, xv.z, xv.w};
      float4 p0 = *(float4*)&TWs[t][tf * 4][0];
      float4 p1 = *(float4*)&TWs[t][tf * 4 + 2][0];
      float c[4] = {p0.x, p0.z, p1.x, p1.z};
      float s[4] = {p0.y, p0.w, p1.y, p1.w};
#pragma unroll
      for (int i = 0; i < 4; ++i)
#pragma unroll
        for (int j = 0; j < 4; ++j) {
          ar[i][j] = fmaf(xx[j], c[i], ar[i][j]);
          ai[i][j] = fmaf(xx[j], s[i], ai[i][j]);
        }
    }
  }
#pragma unroll
  for (int i = 0; i < 4; ++i) {
    int f = f0 + tf * 4 + i;
    if (f >= FLEN) continue;
    float* dst = &xf[((size_t)b * FLEN + f) * NN];
    float o[4];
#pragma unroll
    for (int j = 0; j < 4; ++j)
      o[j] = sqrtf(ar[i][j] * ar[i][j] + ai[i][j] * ai[i][j]);
    int n = n0 + tn * 4;
    if (n + 3 < NN) *(float4*)&dst[n] = make_float4(o[0], o[1], o[2], o[3]);
    else {
#pragma unroll
      for (int j = 0; j < 4; ++j) if (n + j < NN) dst[n + j] = o[j];
    }
  }
}

__global__ void k_colnorm(const float* __restrict__ xf, float* __restrict__ icn) {
  __shared__ float sc[4];
  int bf = blockIdx.x;
  const float* rowp = xf + (size_t)bf * NN;
  float s = 0.f;
  for (int i = threadIdx.x; i < NN; i += 256) { float v = rowp[i]; s = fmaf(v, v, s); }
  s = wredSum(s);
  int lane = threadIdx.x & 63, w = threadIdx.x >> 6;
  if (lane == 0) sc[w] = s;
  __syncthreads();
  if (threadIdx.x == 0)
    icn[bf] = 1.f / fmaxf(sqrtf(sc[0] + sc[1] + sc[2] + sc[3]), 1e-12f);
}

__global__ void k_rownorm(const float* __restrict__ xf, const float* __restrict__ icn,
                          float* __restrict__ irn) {
  int b = blockIdx.y;
  int n = blockIdx.x * 256 + threadIdx.x;
  if (n >= NN) return;
  float s = 0.f;
  for (int f = 0; f < FLEN; ++f) {
    float v = xf[((size_t)b * FLEN + f) * NN + n] * icn[b * FLEN + f];
    s = fmaf(v, v, s);
  }
  irn[b * NN + n] = 1.f / fmaxf(sqrtf(s), 1e-12f);
}

__global__ void k_xe(const float* __restrict__ xf, const float* __restrict__ icn,
                     const float* __restrict__ irn, const float* __restrict__ Ex,
                     float* __restrict__ xe) {
  __shared__ __align__(16) float As[16][64];
  __shared__ __align__(16) float Bs[16][128];
  const int b = blockIdx.y;
  const int n0 = blockIdx.x * 64;
  const int tid = threadIdx.x;
  const int tn = tid >> 4, te = tid & 15;
  float acc[4][8] = {};
  for (int f0 = 0; f0 < 160; f0 += 16) {
    __syncthreads();
    {
      int kt = tid >> 4, q = tid & 15;
      int f = f0 + kt;
      int n = n0 + q * 4;
      float4 v = make_float4(0, 0, 0, 0);
      if (f < FLEN) {
        float ic = icn[b * FLEN + f];
        const float* src = &xf[((size_t)b * FLEN + f) * NN + n];
        if (n + 3 < NN) v = *(const float4*)src;
        else {
          if (n + 0 < NN) v.x = src[0];
          if (n + 1 < NN) v.y = src[1];
          if (n + 2 < NN) v.z = src[2];
          if (n + 3 < NN) v.w = src[3];
        }
        v.x *= ic; v.y *= ic; v.z *= ic; v.w *= ic;
      }
      *(float4*)&As[kt][q * 4] = v;
    }
    for (int l = tid; l < 512; l += 256) {
      int kt = l >> 5, q = l & 31;
      int f = f0 + kt;
      float4 v = make_float4(0, 0, 0, 0);
      if (f < FLEN) v = *(const float4*)&Ex[(size_t)f * EE + q * 4];
      *(float4*)&Bs[kt][q * 4] = v;
    }
    __syncthreads();
#pragma unroll
    for (int k = 0; k < 16; ++k) {
      float4 a  = *(float4*)&As[k][tn * 4];
      float4 b0 = *(float4*)&Bs[k][te * 4];
      float4 b1 = *(float4*)&Bs[k][64 + te * 4];
      float av[4] = {a.x, a.y, a.z, a.w};
      float bv[8] = {b0.x, b0.y, b0.z, b0.w, b1.x, b1.y, b1.z, b1.w};
#pragma unroll
      for (int i = 0; i < 4; ++i)
#pragma unroll
        for (int j = 0; j < 8; ++j)
          acc[i][j] = fmaf(av[i], bv[j], acc[i][j]);
    }
  }
#pragma unroll
  for (int i = 0; i < 4; ++i) {
    int n = n0 + tn * 4 + i;
    if (n >= NN) continue;
    float sc = irn[b * NN + n];
    float* dst = &xe[((size_t)b * NN + n) * EE];
    *(float4*)&dst[te * 4] =
        make_float4(acc[i][0] * sc, acc[i][1] * sc, acc[i][2] * sc, acc[i][3] * sc);
    *(float4*)&dst[64 + te * 4] =
        make_float4(acc[i][4] * sc, acc[i][5] * sc, acc[i][6] * sc, acc[i][7] * sc);
  }
}

// x1 = relu([xe|nodes] . Wd[n]); cooperative float4 Wd streaming.
// Also emits x1 hi/lo fp16 into the (dead after this kernel) xe region,
// interleaved per (b,n) slot: slot base ushort = (b*NN+n)*256; hi at +h, lo at +128+h.
__global__ void k_x1(const float* xe, const float* __restrict__ nodes,
                     const float* __restrict__ Wd, float* __restrict__ x1,
                     ushort_t* x1hl) {
  __shared__ __align__(16) float xk[8][DKK];
  __shared__ float red[4][32][33];
  const int n = blockIdx.x;
  const int tid = threadIdx.x;
  {
    int b = tid >> 5, q = tid & 31;
    *(float4*)&xk[b][q * 4] = *(const float4*)&xe[((size_t)b * NN + n) * EE + q * 4];
  }
  if (tid < 128) {
    int b = tid >> 4, i = tid & 15;
    xk[b][EE + i] = nodes[(size_t)n * IDD + i];
  }
  __syncthreads();
  const int h4 = tid & 31;
  const int dg = tid >> 5;
  float acc[8][4] = {};
  for (int d = dg; d < DKK; d += 8) {
    float4 wv = *(const float4*)&Wd[((size_t)n * DKK + d) * HH + h4 * 4];
#pragma unroll
    for (int b = 0; b < 8; ++b) {
      float xv = xk[b][d];
      acc[b][0] = fmaf(xv, wv.x, acc[b][0]);
      acc[b][1] = fmaf(xv, wv.y, acc[b][1]);
      acc[b][2] = fmaf(xv, wv.z, acc[b][2]);
      acc[b][3] = fmaf(xv, wv.w, acc[b][3]);
    }
  }
#pragma unroll
  for (int b = 0; b < 8; ++b)
#pragma unroll
    for (int j = 0; j < 4; ++j)
      acc[b][j] += __shfl_xor(acc[b][j], 32, 64);
  const int wv_ = tid >> 6, lane = tid & 63;
  if (lane < 32) {
#pragma unroll
    for (int b = 0; b < 8; ++b)
#pragma unroll
      for (int j = 0; j < 4; ++j)
        red[wv_][lane][b * 4 + j] = acc[b][j];
  }
  __syncthreads();
#pragma unroll
  for (int o = 0; o < 4; ++o) {
    int idx = tid + o * 256;
    int b = idx >> 7, h = idx & 127;
    float s = red[0][h >> 2][b * 4 + (h & 3)] + red[1][h >> 2][b * 4 + (h & 3)] +
              red[2][h >> 2][b * 4 + (h & 3)] + red[3][h >> 2][b * 4 + (h & 3)];
    s = fmaxf(s, 0.f);
    x1[((size_t)b * NN + n) * HH + h] = s;
    ushort_t hi, lo;
    split16(s, hi, lo);
    size_t base = ((size_t)b * NN + n) * 256;
    x1hl[base + h] = hi;
    x1hl[base + 128 + h] = lo;
  }
}

__global__ void k_ln_stats(const float* __restrict__ x1, float* __restrict__ lns) {
  __shared__ float sc[4], sc2[4];
  int b = blockIdx.y, chunk = blockIdx.x;
  const float* base = x1 + (size_t)b * NN * HH + (size_t)chunk * 8000;
  float s = 0.f, s2 = 0.f;
  for (int i = threadIdx.x; i < 8000; i += 256) {
    float v = base[i];
    s += v; s2 = fmaf(v, v, s2);
  }
  s = wredSum(s); s2 = wredSum(s2);
  int lane = threadIdx.x & 63, w = threadIdx.x >> 6;
  if (lane == 0) { sc[w] = s; sc2[w] = s2; }
  __syncthreads();
  if (threadIdx.x == 0) {
    atomicAdd(&lns[b], sc[0] + sc[1] + sc[2] + sc[3]);
    atomicAdd(&lns[8 + b], sc2[0] + sc2[1] + sc2[2] + sc2[3]);
  }
}

__global__ void k_ln_final(const float* __restrict__ lns, float* __restrict__ lnf) {
  int b = threadIdx.x;
  if (b < 8) {
    float cnt = (float)(NN * HH);
    float mu = lns[b] / cnt;
    float var = fmaxf(lns[8 + b] / cnt - mu * mu, 0.f);
    lnf[b] = mu;
    lnf[8 + b] = 1.f / sqrtf(var + 1e-8f);
  }
}

// adp = ((x1 . Wx) - mu*colsumW) * inv_sd, emitted directly as fp16 hi/lo
__global__ void k_adp(const float* __restrict__ x1, const float* __restrict__ Wx,
                      const float* __restrict__ csw, const float* __restrict__ lnf,
                      ushort_t* __restrict__ adphl) {
  __shared__ __align__(16) float As[16][64];
  __shared__ __align__(16) float Bs[16][128];
  const int r0 = blockIdx.x * 64;
  const int tid = threadIdx.x;
  const int tn = tid >> 4, te = tid & 15;
  float acc[4][8] = {};
  for (int k0 = 0; k0 < HH; k0 += 16) {
    __syncthreads();
    {
      int rr = tid >> 2, kq = tid & 3;
      float4 v = *(const float4*)&x1[(size_t)(r0 + rr) * HH + k0 + kq * 4];
      As[kq * 4 + 0][rr] = v.x;
      As[kq * 4 + 1][rr] = v.y;
      As[kq * 4 + 2][rr] = v.z;
      As[kq * 4 + 3][rr] = v.w;
    }
    for (int l = tid; l < 512; l += 256) {
      int kt = l >> 5, q = l & 31;
      *(float4*)&Bs[kt][q * 4] = *(const float4*)&Wx[(size_t)(k0 + kt) * HH + q * 4];
    }
    __syncthreads();
#pragma unroll
    for (int k = 0; k < 16; ++k) {
      float4 a  = *(float4*)&As[k][tn * 4];
      float4 b0 = *(float4*)&Bs[k][te * 4];
      float4 b1 = *(float4*)&Bs[k][64 + te * 4];
      float av[4] = {a.x, a.y, a.z, a.w};
      float bv[8] = {b0.x, b0.y, b0.z, b0.w, b1.x, b1.y, b1.z, b1.w};
#pragma unroll
      for (int i = 0; i < 4; ++i)
#pragma unroll
        for (int j = 0; j < 8; ++j)
          acc[i][j] = fmaf(av[i], bv[j], acc[i][j]);
    }
  }
  float4 c0 = *(const float4*)&csw[te * 4];
  float4 c1 = *(const float4*)&csw[64 + te * 4];
  float cw[8] = {c0.x, c0.y, c0.z, c0.w, c1.x, c1.y, c1.z, c1.w};
#pragma unroll
  for (int i = 0; i < 4; ++i) {
    int r = r0 + tn * 4 + i;
    int b = r / NN;
    float mu = lnf[b], isd = lnf[8 + b];
    size_t base = (size_t)r * 256;
    ushort_t hi[8], lo[8];
#pragma unroll
    for (int j = 0; j < 8; ++j) {
      float o = (acc[i][j] - mu * cw[j]) * isd;
      split16(o, hi[j], lo[j]);
    }
    ushort4 u;
    u.x = hi[0]; u.y = hi[1]; u.z = hi[2]; u.w = hi[3];
    *(ushort4*)&adphl[base + te * 4] = u;
    u.x = hi[4]; u.y = hi[5]; u.z = hi[6]; u.w = hi[7];
    *(ushort4*)&adphl[base + 64 + te * 4] = u;
    u.x = lo[0]; u.y = lo[1]; u.z = lo[2]; u.w = lo[3];
    *(ushort4*)&adphl[base + 128 + te * 4] = u;
    u.x = lo[4]; u.y = lo[5]; u.z = lo[6]; u.w = lo[7];
    *(ushort4*)&adphl[base + 128 + 64 + te * 4] = u;
  }
}

// ================= adj GEMM -> relu -> out (fp32, in place in d_out) ==========
// No LDS. 256-thr blocks (4 waves); each block: 16 rows x 512 m; wave w covers
// 128 m (8 subtiles of 16), register-double-buffered B loads straight from
// global (fragment layout row=lane&15, k=quad*8 matches the hl slot layout).
// __launch_bounds__(256,2) lifts the 64-VGPR throttle that defeated the
// double-buffer in the fused version (VGPR_Count=64 < ~115 needed).
__global__ __launch_bounds__(256, 2) void k_adjT(
    const ushort_t* __restrict__ adphl, const ushort_t* __restrict__ x1hl,
    float* __restrict__ out) {
  const int b = blockIdx.z;
  const int n0 = blockIdx.y * 16;
  const int tid = threadIdx.x;
  const int w = tid >> 6;
  const int lane = tid & 63;
  const int quad = lane >> 4, r16 = lane & 15;

  half8 Ah[4], Al[4];
  {
    const ushort_t* abase =
        adphl + ((size_t)(b * NN + n0 + r16)) * 256 + quad * 8;
#pragma unroll
    for (int ks = 0; ks < 4; ++ks) {
      Ah[ks] = *(const half8*)(abase + ks * 32);
      Al[ks] = *(const half8*)(abase + 128 + ks * 32);
    }
  }
  const int mbase = blockIdx.x * 512 + w * 128;  // 8 subtiles of 16
  float* obase = out + ((size_t)(b * NN + n0 + quad * 4)) * NN;

  half8 Bh0[4], Bl0[4], Bh1[4], Bl1[4];

#define LOADB(I, BH, BL)                                                      \
  {                                                                           \
    int mt_ = mbase + (I) * 16 + r16;                                         \
    int mc_ = (mt_ < NN) ? mt_ : NN - 1;                                      \
    const ushort_t* bb_ = x1hl + ((size_t)(b * NN + mc_)) * 256 + quad * 8;   \
    BH[0] = *(const half8*)(bb_);       BL[0] = *(const half8*)(bb_ + 128);   \
    BH[1] = *(const half8*)(bb_ + 32);  BL[1] = *(const half8*)(bb_ + 160);   \
    BH[2] = *(const half8*)(bb_ + 64);  BL[2] = *(const half8*)(bb_ + 192);   \
    BH[3] = *(const half8*)(bb_ + 96);  BL[3] = *(const half8*)(bb_ + 224);   \
  }

#define STEP(I, BH, BL, BH2, BL2)                                             \
  {                                                                           \
    if ((I) < 7) LOADB((I) + 1, BH2, BL2);                                    \
    f32x4 acc = (f32x4){0.f, 0.f, 0.f, 0.f};                                  \
    _Pragma("unroll")                                                         \
    for (int ks = 0; ks < 4; ++ks) {                                          \
      acc = __builtin_amdgcn_mfma_f32_16x16x32_f16(Ah[ks], BH[ks], acc, 0, 0, 0); \
      acc = __builtin_amdgcn_mfma_f32_16x16x32_f16(Ah[ks], BL[ks], acc, 0, 0, 0); \
      acc = __builtin_amdgcn_mfma_f32_16x16x32_f16(Al[ks], BH[ks], acc, 0, 0, 0); \
    }                                                                         \
    int mt_ = mbase + (I) * 16 + r16;                                         \
    if (mt_ < NN) {                                                           \
      _Pragma("unroll")                                                       \
      for (int reg = 0; reg < 4; ++reg)                                       \
        obase[(size_t)reg * NN + mt_] = fmaxf(acc[reg], 0.f);                 \
    }                                                                         \
  }

  LOADB(0, Bh0, Bl0);
  STEP(0, Bh0, Bl0, Bh1, Bl1);
  STEP(1, Bh1, Bl1, Bh0, Bl0);
  STEP(2, Bh0, Bl0, Bh1, Bl1);
  STEP(3, Bh1, Bl1, Bh0, Bl0);
  STEP(4, Bh0, Bl0, Bh1, Bl1);
  STEP(5, Bh1, Bl1, Bh0, Bl0);
  STEP(6, Bh0, Bl0, Bh1, Bl1);
  STEP(7, Bh1, Bl1, Bh0, Bl0);
#undef STEP
#undef LOADB
}

// ================= per-row topk-mask + softmax, in place on d_out =============
// One wave per row, 4 waves/block, 16000 independent waves; row lives in
// registers (V[8] f32x4). topk-20: positive-count -> threshold bisection into
// [20,64] candidates -> ballot-compact to per-wave LDS -> 64-wide bitonic
// sort -> t20 = rank-19 value. No block barriers.
__global__ __launch_bounds__(256, 4) void k_topsm(float* out) {
  __shared__ float scrV[4][64];
  __shared__ int scrI[4][64];
  const int tid = threadIdx.x;
  const int w = tid >> 6, lane = tid & 63;
  const int r = blockIdx.x * 4 + w;  // 0..15999
  float* g = out + (size_t)r * NN;

  f32x4 V[8];  // lane's 32 values: m = j*256 + lane*4 + e
#pragma unroll
  for (int j = 0; j < 8; ++j) {
    int m0 = j * 256 + lane * 4;
    if (m0 < NN) V[j] = *(const f32x4*)&g[m0];
    else V[j] = (f32x4){-1.f, -1.f, -1.f, -1.f};
  }

  float mx = -1.f, cp = 0.f;
#pragma unroll
  for (int j = 0; j < 8; ++j)
#pragma unroll
    for (int e = 0; e < 4; ++e) {
      mx = fmaxf(mx, V[j][e]);
      cp += (V[j][e] > 0.f) ? 1.f : 0.f;
    }
  const float m = wredMaxAll(mx);  // >= 0 (relu)
  const float cpos = wredSumAll(cp);
  const float em = expf(-m);

  if (cpos <= 20.5f) {
    // all positives are in the top-20; zero-ties give identical output
    float s = 0.f;
#pragma unroll
    for (int j = 0; j < 8; ++j)
#pragma unroll
      for (int e = 0; e < 4; ++e)
        if (V[j][e] > 0.f) s += expf(V[j][e] - m);
    s = wredSumAll(s);
    const float invD = 1.f / (s + (2000.f - cpos) * em);
    const float defv = em * invD;
#pragma unroll
    for (int j = 0; j < 8; ++j) {
      int m0 = j * 256 + lane * 4;
      if (m0 >= NN) continue;
      float4 o;
      o.x = (V[j][0] > 0.f) ? expf(V[j][0] - m) * invD : defv;
      o.y = (V[j][1] > 0.f) ? expf(V[j][1] - m) * invD : defv;
      o.z = (V[j][2] > 0.f) ? expf(V[j][2] - m) * invD : defv;
      o.w = (V[j][3] > 0.f) ? expf(V[j][3] - m) * invD : defv;
      *(float4*)&g[m0] = o;
    }
  } else {
    // bracket candidate count into [20,64]
    float tval = 0.f, cf = cpos;
    if (cpos > 64.5f) {
      float tlo = 0.f, thi = m;
      bool found = false;
      for (int it = 0; it < 64 && !found; ++it) {
        float mid = (it < 12)
            ? 0.5f * (tlo + thi)
            : __uint_as_float((__float_as_uint(tlo) + __float_as_uint(thi)) >> 1);
        float c = 0.f;
#pragma unroll
        for (int j = 0; j < 8; ++j)
#pragma unroll
          for (int e = 0; e < 4; ++e)
            c += (V[j][e] > mid) ? 1.f : 0.f;
        c = wredSumAll(c);
        if (c > 64.5f) tlo = mid;
        else if (c < 19.5f) thi = mid;
        else { tval = mid; cf = c; found = true; }
      }
      if (!found) { tval = tlo; cf = 64.f; }  // unreachable for distinct floats
    }
    int cI = (int)(cf + 0.5f);
    if (cI > 64) cI = 64;

    // ballot-compact candidates {v > tval} into per-wave LDS scratch
    float* sv = scrV[w];
    int* si = scrI[w];
    int base = 0;
#pragma unroll
    for (int j = 0; j < 8; ++j)
#pragma unroll
      for (int e = 0; e < 4; ++e) {
        bool p = V[j][e] > tval;
        unsigned long long msk = __ballot(p);
        if (p) {
          int pos = base + (int)__popcll(msk & ((1ull << lane) - 1ull));
          if (pos < 64) { sv[pos] = V[j][e]; si[pos] = j * 256 + lane * 4 + e; }
        }
        base += (int)__popcll(msk);
      }
    asm volatile("s_waitcnt lgkmcnt(0)" ::: "memory");

    float cv = (lane < cI) ? sv[lane] : -1.f;
    int ci = (lane < cI) ? si[lane] : 0x7fffffff;
    // bitonic sort, descending (ties -> lower index first)
#pragma unroll
    for (int k = 2; k <= 64; k <<= 1)
#pragma unroll
      for (int j = k >> 1; j > 0; j >>= 1) {
        float ov = __shfl_xor(cv, j, 64);
        int oi = __shfl_xor(ci, j, 64);
        bool otherBetter = (ov > cv) || (ov == cv && oi < ci);
        bool iAmLow = (lane & j) == 0;
        bool desc = (lane & k) == 0;
        bool take = (desc == iAmLow) ? otherBetter : !otherBetter;
        if (take) { cv = ov; ci = oi; }
      }
    const float t20 = __shfl(cv, 19, 64);  // 20th largest (cI >= 20)
    float e20 = (lane < 20) ? expf(cv - m) : 0.f;
    const float s20 = wredSumAll(e20);
    const float invD = 1.f / (s20 + (2000.f - 20.f) * em);
    const float defv = em * invD;
#pragma unroll
    for (int j = 0; j < 8; ++j) {
      int m0 = j * 256 + lane * 4;
      if (m0 >= NN) continue;
      float4 o;
      o.x = (V[j][0] >= t20) ? expf(V[j][0] - m) * invD : defv;
      o.y = (V[j][1] >= t20) ? expf(V[j][1] - m) * invD : defv;
      o.z = (V[j][2] >= t20) ? expf(V[j][2] - m) * invD : defv;
      o.w = (V[j][3] >= t20) ? expf(V[j][3] - m) * invD : defv;
      *(float4*)&g[m0] = o;
    }
  }
}

extern "C" void kernel_launch(void* const* d_in, const int* in_sizes, int n_in,
                              void* d_out, int out_size, void* d_ws, size_t ws_size,
                              hipStream_t stream) {
  const float* x     = (const float*)d_in[0];
  const float* Ex    = (const float*)d_in[1];
  const float* nodes = (const float*)d_in[2];
  const float* Wd    = (const float*)d_in[3];
  const float* Wx    = (const float*)d_in[4];
  float* out = (float*)d_out;
  float* w = (float*)d_ws;
  float* tw  = w + OFF_TW;
  float* xf  = w + OFF_XF;
  float* icn = w + OFF_ICN;
  float* irn = w + OFF_IRN;
  float* xe  = w + OFF_XE;
  float* x1  = w + OFF_X1;
  float* csw = w + OFF_CSW;
  float* lns = w + OFF_LNS;
  float* lnf = w + OFF_LNF;
  ushort_t* adphl = (ushort_t*)(w + OFF_ADP);
  ushort_t* x1hl  = (ushort_t*)(w + OFF_XE);  // reuses dead xe region

  k_init<<<1, 128, 0, stream>>>(Wx, csw, lns);
  k_tw<<<(TT * FLEN + 255) / 256, 256, 0, stream>>>(tw);
  k_dft<<<dim3(16, 5, BB), 256, 0, stream>>>(x, tw, xf);
  k_colnorm<<<BB * FLEN, 256, 0, stream>>>(xf, icn);
  k_rownorm<<<dim3(8, BB), 256, 0, stream>>>(xf, icn, irn);
  k_xe<<<dim3(32, BB), 256, 0, stream>>>(xf, icn, irn, Ex, xe);
  k_x1<<<NN, 256, 0, stream>>>(xe, nodes, Wd, x1, x1hl);
  k_ln_stats<<<dim3(32, BB), 256, 0, stream>>>(x1, lns);
  k_ln_final<<<1, 64, 0, stream>>>(lns, lnf);
  k_adp<<<250, 256, 0, stream>>>(x1, Wx, csw, lnf, adphl);
  k_adjT<<<dim3(4, 125, BB), 256, 0, stream>>>(adphl, x1hl, out);
  k_topsm<<<(BB * NN) / 4, 256, 0, stream>>>(out);
}

// Round 6
// 490.747 us; speedup vs baseline: 1.1864x; 1.1640x over previous
//
#include <hip/hip_runtime.h>
#include <math.h>

#define BB 8
#define TT 288
#define NN 2000
#define FLEN 145
#define EE 128
#define IDD 16
#define HH 128
#define DKK 144
#define KTOP 20

typedef _Float16 half8 __attribute__((ext_vector_type(8)));
typedef float f32x4 __attribute__((ext_vector_type(4)));
typedef unsigned short ushort_t;

// ---- workspace layout (float offsets) ----
#define OFF_TW  ((size_t)0)
#define SZ_TW   ((size_t)TT*FLEN*2)
#define OFF_XF  (OFF_TW + SZ_TW)
#define SZ_XF   ((size_t)BB*FLEN*NN)
#define OFF_ICN (OFF_XF + SZ_XF)
#define OFF_IRN (OFF_ICN + (size_t)BB*FLEN)
#define OFF_XE  (OFF_IRN + (size_t)BB*NN)   // after k_x1 consumes xe, region is reused as x1 hi/lo fp16 (fragment-tiled)
#define SZ_BNH  ((size_t)BB*NN*HH)
#define OFF_X1  (OFF_XE + SZ_BNH)
#define OFF_ADP (OFF_X1 + SZ_BNH)           // holds adp hi/lo fp16 (fragment-tiled), never fp32
#define OFF_CSW (OFF_ADP + SZ_BNH)
#define OFF_LNS (OFF_CSW + HH)
#define OFF_LNF (OFF_LNS + 16)

// Fragment-tiled hi/lo layout (NN = 125*16 exactly):
//   ushort offset = (b*125 + (n>>4))*4096 + hl*2048 + (k>>5)*512
//                 + ((k>>3)&3)*128 + (n&15)*8 + (k&7)
// A wave's MFMA fragment load (lane = quad*16+r16, need row n0+r16, k=ks*32+quad*8..+7)
// becomes ONE contiguous 1KB read: base + ks*512 + quad*128 + r16*8.
// The old per-row slot layout made every fragment load a 16-segment 64B gather
// (16x transaction amplification) -- that was k_adjT's 2700cyc/STEP stall.

__device__ __forceinline__ float wredSum(float v) {
#pragma unroll
  for (int o = 32; o > 0; o >>= 1) v += __shfl_down(v, o, 64);
  return v;
}
__device__ __forceinline__ float wredMax(float v) {
#pragma unroll
  for (int o = 32; o > 0; o >>= 1) v = fmaxf(v, __shfl_down(v, o, 64));
  return v;
}
// butterfly variants: result valid in ALL lanes (no broadcast needed)
__device__ __forceinline__ float wredSumAll(float v) {
#pragma unroll
  for (int o = 32; o > 0; o >>= 1) v += __shfl_xor(v, o, 64);
  return v;
}
__device__ __forceinline__ float wredMaxAll(float v) {
#pragma unroll
  for (int o = 32; o > 0; o >>= 1) v = fmaxf(v, __shfl_xor(v, o, 64));
  return v;
}

// fp16 hi/lo split: v = hi + lo + O(2^-22 * v)
__device__ __forceinline__ void split16(float v, ushort_t& hi, ushort_t& lo) {
  _Float16 h = (_Float16)v;
  _Float16 l = (_Float16)(v - (float)h);
  union { _Float16 f; ushort_t u; } a, b;
  a.f = h; b.f = l;
  hi = a.u; lo = b.u;
}

// colsum of Wxabs + zero LN accumulators
__global__ void k_init(const float* __restrict__ Wx, float* __restrict__ csw,
                       float* __restrict__ lns) {
  int k = threadIdx.x;
  float s = 0.f;
  for (int h = 0; h < HH; ++h) s += Wx[h * HH + k];
  csw[k] = s;
  if (k < 16) lns[k] = 0.f;
}

// twiddles: exact int reduction of angle
__global__ void k_tw(float* __restrict__ tw) {
  int id = blockIdx.x * 256 + threadIdx.x;
  if (id >= TT * FLEN) return;
  int t = id / FLEN, f = id % FLEN;
  int r = (t * f) % TT;
  double th = -2.0 * 3.14159265358979323846 * (double)r / (double)TT;
  tw[2 * id]     = (float)cos(th);
  tw[2 * id + 1] = (float)sin(th);
}

// xf[b][f][n] = |rfft(x[b,:,n])[f]|
__global__ void k_dft(const float* __restrict__ x, const float* __restrict__ tw,
                      float* __restrict__ xf) {
  __shared__ __align__(16) float Xs[16][128];
  __shared__ __align__(16) float TWs[16][32][2];
  const int b = blockIdx.z;
  const int f0 = blockIdx.y * 32;
  const int n0 = blockIdx.x * 128;
  const int tid = threadIdx.x;
  const int tn = tid & 31;
  const int tf = tid >> 5;
  float ar[4][4] = {}, ai[4][4] = {};
  for (int t0 = 0; t0 < TT; t0 += 16) {
    __syncthreads();
    for (int l = tid; l < 512; l += 256) {
      int row = l >> 5, q = l & 31;
      int n = n0 + q * 4;
      const float* src = x + ((size_t)b * TT + (t0 + row)) * NN + n;
      float4 v = make_float4(0, 0, 0, 0);
      if (n + 3 < NN) v = *(const float4*)src;
      else {
        if (n + 0 < NN) v.x = src[0];
        if (n + 1 < NN) v.y = src[1];
        if (n + 2 < NN) v.z = src[2];
        if (n + 3 < NN) v.w = src[3];
      }
      *(float4*)&Xs[row][q * 4] = v;
    }
    for (int l = tid; l < 512; l += 256) {
      int row = l >> 5, ff = l & 31;
      int f = f0 + ff;
      float2 cs = make_float2(0, 0);
      if (f < FLEN) cs = *(const float2*)&tw[((size_t)(t0 + row) * FLEN + f) * 2];
      *(float2*)&TWs[row][ff][0] = cs;
    }
    __syncthreads();
#pragma unroll 4
    for (int t = 0; t < 16; ++t) {
      float4 xv = *(float4*)&Xs[t][tn * 4];
      float xx[4] = {xv.x, xv.y, xv.z, xv.w};
      float4 p0 = *(float4*)&TWs[t][tf * 4][0];
      float4 p1 = *(float4*)&TWs[t][tf * 4 + 2][0];
      float c[4] = {p0.x, p0.z, p1.x, p1.z};
      float s[4] = {p0.y, p0.w, p1.y, p1.w};
#pragma unroll
      for (int i = 0; i < 4; ++i)
#pragma unroll
        for (int j = 0; j < 4; ++j) {
          ar[i][j] = fmaf(xx[j], c[i], ar[i][j]);
          ai[i][j] = fmaf(xx[j], s[i], ai[i][j]);
        }
    }
  }
#pragma unroll
  for (int i = 0; i < 4; ++i) {
    int f = f0 + tf * 4 + i;
    if (f >= FLEN) continue;
    float* dst = &xf[((size_t)b * FLEN + f) * NN];
    float o[4];
#pragma unroll
    for (int j = 0; j < 4; ++j)
      o[j] = sqrtf(ar[i][j] * ar[i][j] + ai[i][j] * ai[i][j]);
    int n = n0 + tn * 4;
    if (n + 3 < NN) *(float4*)&dst[n] = make_float4(o[0], o[1], o[2], o[3]);
    else {
#pragma unroll
      for (int j = 0; j < 4; ++j) if (n + j < NN) dst[n + j] = o[j];
    }
  }
}

__global__ void k_colnorm(const float* __restrict__ xf, float* __restrict__ icn) {
  __shared__ float sc[4];
  int bf = blockIdx.x;
  const float* rowp = xf + (size_t)bf * NN;
  float s = 0.f;
  for (int i = threadIdx.x; i < NN; i += 256) { float v = rowp[i]; s = fmaf(v, v, s); }
  s = wredSum(s);
  int lane = threadIdx.x & 63, w = threadIdx.x >> 6;
  if (lane == 0) sc[w] = s;
  __syncthreads();
  if (threadIdx.x == 0)
    icn[bf] = 1.f / fmaxf(sqrtf(sc[0] + sc[1] + sc[2] + sc[3]), 1e-12f);
}

__global__ void k_rownorm(const float* __restrict__ xf, const float* __restrict__ icn,
                          float* __restrict__ irn) {
  int b = blockIdx.y;
  int n = blockIdx.x * 256 + threadIdx.x;
  if (n >= NN) return;
  float s = 0.f;
  for (int f = 0; f < FLEN; ++f) {
    float v = xf[((size_t)b * FLEN + f) * NN + n] * icn[b * FLEN + f];
    s = fmaf(v, v, s);
  }
  irn[b * NN + n] = 1.f / fmaxf(sqrtf(s), 1e-12f);
}

__global__ void k_xe(const float* __restrict__ xf, const float* __restrict__ icn,
                     const float* __restrict__ irn, const float* __restrict__ Ex,
                     float* __restrict__ xe) {
  __shared__ __align__(16) float As[16][64];
  __shared__ __align__(16) float Bs[16][128];
  const int b = blockIdx.y;
  const int n0 = blockIdx.x * 64;
  const int tid = threadIdx.x;
  const int tn = tid >> 4, te = tid & 15;
  float acc[4][8] = {};
  for (int f0 = 0; f0 < 160; f0 += 16) {
    __syncthreads();
    {
      int kt = tid >> 4, q = tid & 15;
      int f = f0 + kt;
      int n = n0 + q * 4;
      float4 v = make_float4(0, 0, 0, 0);
      if (f < FLEN) {
        float ic = icn[b * FLEN + f];
        const float* src = &xf[((size_t)b * FLEN + f) * NN + n];
        if (n + 3 < NN) v = *(const float4*)src;
        else {
          if (n + 0 < NN) v.x = src[0];
          if (n + 1 < NN) v.y = src[1];
          if (n + 2 < NN) v.z = src[2];
          if (n + 3 < NN) v.w = src[3];
        }
        v.x *= ic; v.y *= ic; v.z *= ic; v.w *= ic;
      }
      *(float4*)&As[kt][q * 4] = v;
    }
    for (int l = tid; l < 512; l += 256) {
      int kt = l >> 5, q = l & 31;
      int f = f0 + kt;
      float4 v = make_float4(0, 0, 0, 0);
      if (f < FLEN) v = *(const float4*)&Ex[(size_t)f * EE + q * 4];
      *(float4*)&Bs[kt][q * 4] = v;
    }
    __syncthreads();
#pragma unroll
    for (int k = 0; k < 16; ++k) {
      float4 a  = *(float4*)&As[k][tn * 4];
      float4 b0 = *(float4*)&Bs[k][te * 4];
      float4 b1 = *(float4*)&Bs[k][64 + te * 4];
      float av[4] = {a.x, a.y, a.z, a.w};
      float bv[8] = {b0.x, b0.y, b0.z, b0.w, b1.x, b1.y, b1.z, b1.w};
#pragma unroll
      for (int i = 0; i < 4; ++i)
#pragma unroll
        for (int j = 0; j < 8; ++j)
          acc[i][j] = fmaf(av[i], bv[j], acc[i][j]);
    }
  }
#pragma unroll
  for (int i = 0; i < 4; ++i) {
    int n = n0 + tn * 4 + i;
    if (n >= NN) continue;
    float sc = irn[b * NN + n];
    float* dst = &xe[((size_t)b * NN + n) * EE];
    *(float4*)&dst[te * 4] =
        make_float4(acc[i][0] * sc, acc[i][1] * sc, acc[i][2] * sc, acc[i][3] * sc);
    *(float4*)&dst[64 + te * 4] =
        make_float4(acc[i][4] * sc, acc[i][5] * sc, acc[i][6] * sc, acc[i][7] * sc);
  }
}

// x1 = relu([xe|nodes] . Wd[n]); cooperative float4 Wd streaming.
// Emits x1 hi/lo fp16 into the dead xe region in FRAGMENT-TILED layout (see top).
__global__ void k_x1(const float* xe, const float* __restrict__ nodes,
                     const float* __restrict__ Wd, float* __restrict__ x1,
                     ushort_t* x1hl) {
  __shared__ __align__(16) float xk[8][DKK];
  __shared__ float red[4][32][33];
  const int n = blockIdx.x;
  const int tid = threadIdx.x;
  {
    int b = tid >> 5, q = tid & 31;
    *(float4*)&xk[b][q * 4] = *(const float4*)&xe[((size_t)b * NN + n) * EE + q * 4];
  }
  if (tid < 128) {
    int b = tid >> 4, i = tid & 15;
    xk[b][EE + i] = nodes[(size_t)n * IDD + i];
  }
  __syncthreads();
  const int h4 = tid & 31;
  const int dg = tid >> 5;
  float acc[8][4] = {};
  for (int d = dg; d < DKK; d += 8) {
    float4 wv = *(const float4*)&Wd[((size_t)n * DKK + d) * HH + h4 * 4];
#pragma unroll
    for (int b = 0; b < 8; ++b) {
      float xv = xk[b][d];
      acc[b][0] = fmaf(xv, wv.x, acc[b][0]);
      acc[b][1] = fmaf(xv, wv.y, acc[b][1]);
      acc[b][2] = fmaf(xv, wv.z, acc[b][2]);
      acc[b][3] = fmaf(xv, wv.w, acc[b][3]);
    }
  }
#pragma unroll
  for (int b = 0; b < 8; ++b)
#pragma unroll
    for (int j = 0; j < 4; ++j)
      acc[b][j] += __shfl_xor(acc[b][j], 32, 64);
  const int wv_ = tid >> 6, lane = tid & 63;
  if (lane < 32) {
#pragma unroll
    for (int b = 0; b < 8; ++b)
#pragma unroll
      for (int j = 0; j < 4; ++j)
        red[wv_][lane][b * 4 + j] = acc[b][j];
  }
  __syncthreads();
  const size_t tbase = (size_t)(n >> 4) * 4096 + (size_t)(n & 15) * 8;
#pragma unroll
  for (int o = 0; o < 4; ++o) {
    int idx = tid + o * 256;
    int b = idx >> 7, h = idx & 127;
    float s = red[0][h >> 2][b * 4 + (h & 3)] + red[1][h >> 2][b * 4 + (h & 3)] +
              red[2][h >> 2][b * 4 + (h & 3)] + red[3][h >> 2][b * 4 + (h & 3)];
    s = fmaxf(s, 0.f);
    x1[((size_t)b * NN + n) * HH + h] = s;
    ushort_t hi, lo;
    split16(s, hi, lo);
    size_t slot = (size_t)b * (125 * 4096) + tbase +
                  (size_t)((h >> 5) * 512 + ((h >> 3) & 3) * 128 + (h & 7));
    x1hl[slot] = hi;
    x1hl[slot + 2048] = lo;
  }
}

__global__ void k_ln_stats(const float* __restrict__ x1, float* __restrict__ lns) {
  __shared__ float sc[4], sc2[4];
  int b = blockIdx.y, chunk = blockIdx.x;
  const float* base = x1 + (size_t)b * NN * HH + (size_t)chunk * 8000;
  float s = 0.f, s2 = 0.f;
  for (int i = threadIdx.x; i < 8000; i += 256) {
    float v = base[i];
    s += v; s2 = fmaf(v, v, s2);
  }
  s = wredSum(s); s2 = wredSum(s2);
  int lane = threadIdx.x & 63, w = threadIdx.x >> 6;
  if (lane == 0) { sc[w] = s; sc2[w] = s2; }
  __syncthreads();
  if (threadIdx.x == 0) {
    atomicAdd(&lns[b], sc[0] + sc[1] + sc[2] + sc[3]);
    atomicAdd(&lns[8 + b], sc2[0] + sc2[1] + sc2[2] + sc2[3]);
  }
}

__global__ void k_ln_final(const float* __restrict__ lns, float* __restrict__ lnf) {
  int b = threadIdx.x;
  if (b < 8) {
    float cnt = (float)(NN * HH);
    float mu = lns[b] / cnt;
    float var = fmaxf(lns[8 + b] / cnt - mu * mu, 0.f);
    lnf[b] = mu;
    lnf[8 + b] = 1.f / sqrtf(var + 1e-8f);
  }
}

// adp = ((x1 . Wx) - mu*colsumW) * inv_sd, emitted as fp16 hi/lo fragment-tiled
__global__ void k_adp(const float* __restrict__ x1, const float* __restrict__ Wx,
                      const float* __restrict__ csw, const float* __restrict__ lnf,
                      ushort_t* __restrict__ adphl) {
  __shared__ __align__(16) float As[16][64];
  __shared__ __align__(16) float Bs[16][128];
  const int r0 = blockIdx.x * 64;
  const int tid = threadIdx.x;
  const int tn = tid >> 4, te = tid & 15;
  float acc[4][8] = {};
  for (int k0 = 0; k0 < HH; k0 += 16) {
    __syncthreads();
    {
      int rr = tid >> 2, kq = tid & 3;
      float4 v = *(const float4*)&x1[(size_t)(r0 + rr) * HH + k0 + kq * 4];
      As[kq * 4 + 0][rr] = v.x;
      As[kq * 4 + 1][rr] = v.y;
      As[kq * 4 + 2][rr] = v.z;
      As[kq * 4 + 3][rr] = v.w;
    }
    for (int l = tid; l < 512; l += 256) {
      int kt = l >> 5, q = l & 31;
      *(float4*)&Bs[kt][q * 4] = *(const float4*)&Wx[(size_t)(k0 + kt) * HH + q * 4];
    }
    __syncthreads();
#pragma unroll
    for (int k = 0; k < 16; ++k) {
      float4 a  = *(float4*)&As[k][tn * 4];
      float4 b0 = *(float4*)&Bs[k][te * 4];
      float4 b1 = *(float4*)&Bs[k][64 + te * 4];
      float av[4] = {a.x, a.y, a.z, a.w};
      float bv[8] = {b0.x, b0.y, b0.z, b0.w, b1.x, b1.y, b1.z, b1.w};
#pragma unroll
      for (int i = 0; i < 4; ++i)
#pragma unroll
        for (int j = 0; j < 8; ++j)
          acc[i][j] = fmaf(av[i], bv[j], acc[i][j]);
    }
  }
  float4 c0 = *(const float4*)&csw[te * 4];
  float4 c1 = *(const float4*)&csw[64 + te * 4];
  float cw[8] = {c0.x, c0.y, c0.z, c0.w, c1.x, c1.y, c1.z, c1.w};
  const int c0k = te * 4, c1k = 64 + te * 4;
  const size_t o0r = (size_t)((c0k >> 5) * 512 + ((c0k >> 3) & 3) * 128 + (c0k & 7));
  const size_t o1r = (size_t)((c1k >> 5) * 512 + ((c1k >> 3) & 3) * 128 + (c1k & 7));
#pragma unroll
  for (int i = 0; i < 4; ++i) {
    int r = r0 + tn * 4 + i;
    int b = r / NN, n = r % NN;
    float mu = lnf[b], isd = lnf[8 + b];
    ushort_t hi[8], lo[8];
#pragma unroll
    for (int j = 0; j < 8; ++j) {
      float o = (acc[i][j] - mu * cw[j]) * isd;
      split16(o, hi[j], lo[j]);
    }
    size_t slot = (size_t)b * (125 * 4096) + (size_t)(n >> 4) * 4096 +
                  (size_t)(n & 15) * 8;
    ushort4 u;
    u.x = hi[0]; u.y = hi[1]; u.z = hi[2]; u.w = hi[3];
    *(ushort4*)&adphl[slot + o0r] = u;
    u.x = hi[4]; u.y = hi[5]; u.z = hi[6]; u.w = hi[7];
    *(ushort4*)&adphl[slot + o1r] = u;
    u.x = lo[0]; u.y = lo[1]; u.z = lo[2]; u.w = lo[3];
    *(ushort4*)&adphl[slot + 2048 + o0r] = u;
    u.x = lo[4]; u.y = lo[5]; u.z = lo[6]; u.w = lo[7];
    *(ushort4*)&adphl[slot + 2048 + o1r] = u;
  }
}

// ================= adj GEMM -> relu -> out (fp32, in place in d_out) ==========
// Fragment-tiled operands: every A/B fragment load is ONE contiguous 1KB
// instruction (was a 16-segment 64B gather -> 2700cyc/STEP latency stall).
// Register-double-buffered B with sched_barrier(0) pinning the prefetch order
// (round-2's prefetch was silently rematerialized: VGPR_Count=44).
__global__ __launch_bounds__(256, 2) void k_adjT(
    const ushort_t* __restrict__ adphl, const ushort_t* __restrict__ x1hl,
    float* __restrict__ out) {
  const int b = blockIdx.z;
  const int tA = blockIdx.y;          // n-tile 0..124
  const int n0 = tA * 16;
  const int tid = threadIdx.x;
  const int w = tid >> 6;
  const int lane = tid & 63;
  const int quad = lane >> 4, r16 = lane & 15;
  const int lq = quad * 128 + r16 * 8;  // fragment lane offset (ushorts)

  half8 Ah[4], Al[4];
  {
    const ushort_t* abase = adphl + ((size_t)(b * 125 + tA)) * 4096 + lq;
#pragma unroll
    for (int ks = 0; ks < 4; ++ks) {
      Ah[ks] = *(const half8*)(abase + ks * 512);
      Al[ks] = *(const half8*)(abase + 2048 + ks * 512);
    }
  }
  const int mbase = blockIdx.x * 512 + w * 128;  // 8 subtiles of 16
  const ushort_t* Bb = x1hl + (size_t)b * (125 * 4096) + lq;
  float* obase = out + ((size_t)(b * NN + n0 + quad * 4)) * NN;

  half8 Bh0[4], Bl0[4], Bh1[4], Bl1[4];

#define LOADB(I, BH, BL)                                                      \
  {                                                                           \
    int tB_ = (mbase + (I) * 16) >> 4;                                        \
    if (tB_ > 124) tB_ = 124; /* m-subtiles >=2000 are store-masked */        \
    const ushort_t* bb_ = Bb + (size_t)tB_ * 4096;                            \
    BH[0] = *(const half8*)(bb_);        BL[0] = *(const half8*)(bb_ + 2048); \
    BH[1] = *(const half8*)(bb_ + 512);  BL[1] = *(const half8*)(bb_ + 2560); \
    BH[2] = *(const half8*)(bb_ + 1024); BL[2] = *(const half8*)(bb_ + 3072); \
    BH[3] = *(const half8*)(bb_ + 1536); BL[3] = *(const half8*)(bb_ + 3584); \
  }

#define STEP(I, BH, BL, BH2, BL2)                                             \
  {                                                                           \
    if ((I) < 7) LOADB((I) + 1, BH2, BL2);                                    \
    __builtin_amdgcn_sched_barrier(0); /* pin prefetch above the MFMAs */     \
    f32x4 acc = (f32x4){0.f, 0.f, 0.f, 0.f};                                  \
    _Pragma("unroll")                                                         \
    for (int ks = 0; ks < 4; ++ks) {                                          \
      acc = __builtin_amdgcn_mfma_f32_16x16x32_f16(Ah[ks], BH[ks], acc, 0, 0, 0); \
      acc = __builtin_amdgcn_mfma_f32_16x16x32_f16(Ah[ks], BL[ks], acc, 0, 0, 0); \
      acc = __builtin_amdgcn_mfma_f32_16x16x32_f16(Al[ks], BH[ks], acc, 0, 0, 0); \
    }                                                                         \
    int mt_ = mbase + (I) * 16 + r16;                                         \
    if (mt_ < NN) {                                                           \
      _Pragma("unroll")                                                       \
      for (int reg = 0; reg < 4; ++reg)                                       \
        obase[(size_t)reg * NN + mt_] = fmaxf(acc[reg], 0.f);                 \
    }                                                                         \
  }

  LOADB(0, Bh0, Bl0);
  STEP(0, Bh0, Bl0, Bh1, Bl1);
  STEP(1, Bh1, Bl1, Bh0, Bl0);
  STEP(2, Bh0, Bl0, Bh1, Bl1);
  STEP(3, Bh1, Bl1, Bh0, Bl0);
  STEP(4, Bh0, Bl0, Bh1, Bl1);
  STEP(5, Bh1, Bl1, Bh0, Bl0);
  STEP(6, Bh0, Bl0, Bh1, Bl1);
  STEP(7, Bh1, Bl1, Bh0, Bl0);
#undef STEP
#undef LOADB
}

// ================= per-row topk-mask + softmax, in place on d_out =============
// One wave per row, 4 waves/block, 16000 independent waves; row lives in
// registers (V[8] f32x4). topk-20: positive-count -> threshold bisection into
// [20,64] candidates -> ballot-compact to per-wave LDS -> 64-wide bitonic
// sort -> t20 = rank-19 value. No block barriers.
__global__ __launch_bounds__(256, 4) void k_topsm(float* out) {
  __shared__ float scrV[4][64];
  __shared__ int scrI[4][64];
  const int tid = threadIdx.x;
  const int w = tid >> 6, lane = tid & 63;
  const int r = blockIdx.x * 4 + w;  // 0..15999
  float* g = out + (size_t)r * NN;

  f32x4 V[8];  // lane's 32 values: m = j*256 + lane*4 + e
#pragma unroll
  for (int j = 0; j < 8; ++j) {
    int m0 = j * 256 + lane * 4;
    if (m0 < NN) V[j] = *(const f32x4*)&g[m0];
    else V[j] = (f32x4){-1.f, -1.f, -1.f, -1.f};
  }

  float mx = -1.f, cp = 0.f;
#pragma unroll
  for (int j = 0; j < 8; ++j)
#pragma unroll
    for (int e = 0; e < 4; ++e) {
      mx = fmaxf(mx, V[j][e]);
      cp += (V[j][e] > 0.f) ? 1.f : 0.f;
    }
  const float m = wredMaxAll(mx);  // >= 0 (relu)
  const float cpos = wredSumAll(cp);
  const float em = expf(-m);

  if (cpos <= 20.5f) {
    // all positives are in the top-20; zero-ties give identical output
    float s = 0.f;
#pragma unroll
    for (int j = 0; j < 8; ++j)
#pragma unroll
      for (int e = 0; e < 4; ++e)
        if (V[j][e] > 0.f) s += expf(V[j][e] - m);
    s = wredSumAll(s);
    const float invD = 1.f / (s + (2000.f - cpos) * em);
    const float defv = em * invD;
#pragma unroll
    for (int j = 0; j < 8; ++j) {
      int m0 = j * 256 + lane * 4;
      if (m0 >= NN) continue;
      float4 o;
      o.x = (V[j][0] > 0.f) ? expf(V[j][0] - m) * invD : defv;
      o.y = (V[j][1] > 0.f) ? expf(V[j][1] - m) * invD : defv;
      o.z = (V[j][2] > 0.f) ? expf(V[j][2] - m) * invD : defv;
      o.w = (V[j][3] > 0.f) ? expf(V[j][3] - m) * invD : defv;
      *(float4*)&g[m0] = o;
    }
  } else {
    // bracket candidate count into [20,64]
    float tval = 0.f, cf = cpos;
    if (cpos > 64.5f) {
      float tlo = 0.f, thi = m;
      bool found = false;
      for (int it = 0; it < 64 && !found; ++it) {
        float mid = (it < 12)
            ? 0.5f * (tlo + thi)
            : __uint_as_float((__float_as_uint(tlo) + __float_as_uint(thi)) >> 1);
        float c = 0.f;
#pragma unroll
        for (int j = 0; j < 8; ++j)
#pragma unroll
          for (int e = 0; e < 4; ++e)
            c += (V[j][e] > mid) ? 1.f : 0.f;
        c = wredSumAll(c);
        if (c > 64.5f) tlo = mid;
        else if (c < 19.5f) thi = mid;
        else { tval = mid; cf = c; found = true; }
      }
      if (!found) { tval = tlo; cf = 64.f; }  // unreachable for distinct floats
    }
    int cI = (int)(cf + 0.5f);
    if (cI > 64) cI = 64;

    // ballot-compact candidates {v > tval} into per-wave LDS scratch
    float* sv = scrV[w];
    int* si = scrI[w];
    int base = 0;
#pragma unroll
    for (int j = 0; j < 8; ++j)
#pragma unroll
      for (int e = 0; e < 4; ++e) {
        bool p = V[j][e] > tval;
        unsigned long long msk = __ballot(p);
        if (p) {
          int pos = base + (int)__popcll(msk & ((1ull << lane) - 1ull));
          if (pos < 64) { sv[pos] = V[j][e]; si[pos] = j * 256 + lane * 4 + e; }
        }
        base += (int)__popcll(msk);
      }
    asm volatile("s_waitcnt lgkmcnt(0)" ::: "memory");

    float cv = (lane < cI) ? sv[lane] : -1.f;
    int ci = (lane < cI) ? si[lane] : 0x7fffffff;
    // bitonic sort, descending (ties -> lower index first)
#pragma unroll
    for (int k = 2; k <= 64; k <<= 1)
#pragma unroll
      for (int j = k >> 1; j > 0; j >>= 1) {
        float ov = __shfl_xor(cv, j, 64);
        int oi = __shfl_xor(ci, j, 64);
        bool otherBetter = (ov > cv) || (ov == cv && oi < ci);
        bool iAmLow = (lane & j) == 0;
        bool desc = (lane & k) == 0;
        bool take = (desc == iAmLow) ? otherBetter : !otherBetter;
        if (take) { cv = ov; ci = oi; }
      }
    const float t20 = __shfl(cv, 19, 64);  // 20th largest (cI >= 20)
    float e20 = (lane < 20) ? expf(cv - m) : 0.f;
    const float s20 = wredSumAll(e20);
    const float invD = 1.f / (s20 + (2000.f - 20.f) * em);
    const float defv = em * invD;
#pragma unroll
    for (int j = 0; j < 8; ++j) {
      int m0 = j * 256 + lane * 4;
      if (m0 >= NN) continue;
      float4 o;
      o.x = (V[j][0] >= t20) ? expf(V[j][0] - m) * invD : defv;
      o.y = (V[j][1] >= t20) ? expf(V[j][1] - m) * invD : defv;
      o.z = (V[j][2] >= t20) ? expf(V[j][2] - m) * invD : defv;
      o.w = (V[j][3] >= t20) ? expf(V[j][3] - m) * invD : defv;
      *(float4*)&g[m0] = o;
    }
  }
}

extern "C" void kernel_launch(void* const* d_in, const int* in_sizes, int n_in,
                              void* d_out, int out_size, void* d_ws, size_t ws_size,
                              hipStream_t stream) {
  const float* x     = (const float*)d_in[0];
  const float* Ex    = (const float*)d_in[1];
  const float* nodes = (const float*)d_in[2];
  const float* Wd    = (const float*)d_in[3];
  const float* Wx    = (const float*)d_in[4];
  float* out = (float*)d_out;
  float* w = (float*)d_ws;
  float* tw  = w + OFF_TW;
  float* xf  = w + OFF_XF;
  float* icn = w + OFF_ICN;
  float* irn = w + OFF_IRN;
  float* xe  = w + OFF_XE;
  float* x1  = w + OFF_X1;
  float* csw = w + OFF_CSW;
  float* lns = w + OFF_LNS;
  float* lnf = w + OFF_LNF;
  ushort_t* adphl = (ushort_t*)(w + OFF_ADP);
  ushort_t* x1hl  = (ushort_t*)(w + OFF_XE);  // reuses dead xe region

  k_init<<<1, 128, 0, stream>>>(Wx, csw, lns);
  k_tw<<<(TT * FLEN + 255) / 256, 256, 0, stream>>>(tw);
  k_dft<<<dim3(16, 5, BB), 256, 0, stream>>>(x, tw, xf);
  k_colnorm<<<BB * FLEN, 256, 0, stream>>>(xf, icn);
  k_rownorm<<<dim3(8, BB), 256, 0, stream>>>(xf, icn, irn);
  k_xe<<<dim3(32, BB), 256, 0, stream>>>(xf, icn, irn, Ex, xe);
  k_x1<<<NN, 256, 0, stream>>>(xe, nodes, Wd, x1, x1hl);
  k_ln_stats<<<dim3(32, BB), 256, 0, stream>>>(x1, lns);
  k_ln_final<<<1, 64, 0, stream>>>(lns, lnf);
  k_adp<<<250, 256, 0, stream>>>(x1, Wx, csw, lnf, adphl);
  k_adjT<<<dim3(4, 125, BB), 256, 0, stream>>>(adphl, x1hl, out);
  k_topsm<<<(BB * NN) / 4, 256, 0, stream>>>(out);
}